// Round 12
// baseline (1387.309 us; speedup 1.0000x reference)
//
#include <hip/hip_runtime.h>
#include <hip/hip_bf16.h>

typedef __attribute__((ext_vector_type(4))) float f32x4;
typedef __attribute__((ext_vector_type(8))) short short8;
typedef __attribute__((ext_vector_type(8))) unsigned short ushort8;
typedef __attribute__((ext_vector_type(4))) unsigned short ushort4v;
typedef __attribute__((ext_vector_type(4))) unsigned int uint4v;

#define DEVFN __device__ __forceinline__

DEVFN float b2f(unsigned short u) { return __uint_as_float(((unsigned)u) << 16); }
DEVFN unsigned short f2b(float f) {
  __hip_bfloat16 h = __float2bfloat16(f);
  return __builtin_bit_cast(unsigned short, h);
}

DEVFN void load_lds16(const void* g, void* l) {
  __builtin_amdgcn_global_load_lds(
      (const __attribute__((address_space(1))) unsigned int*)g,
      (__attribute__((address_space(3))) unsigned int*)l, 16, 0, 0);
}

// ===========================================================================

__global__ void fill_out_zero(float* o, int n) {
  int i = blockIdx.x * 256 + threadIdx.x;
  if (i < n) o[i] = 0.0f;
}

__global__ __launch_bounds__(256) void init_x(
    const float* __restrict__ xin, const float* __restrict__ bvec,
    float* __restrict__ x, unsigned short* __restrict__ xb) {
  size_t i = (size_t)blockIdx.x * 256 + threadIdx.x;
  int col = (int)(i % 768);
  float v = xin[i] - bvec[col];
  x[i] = v;
  xb[i] = f2b(v);
}

// buf[i] = bias[i % ld] (or 0 if bias null)
__global__ __launch_bounds__(256) void fill_bias(
    float* __restrict__ buf, const float* __restrict__ bias, int ld) {
  size_t i = (size_t)blockIdx.x * 256 + threadIdx.x;
  buf[i] = bias ? bias[(int)(i % ld)] : 0.0f;
}

// f32 -> bf16 straight convert, 4 elems/thread (n must be /1024)
__global__ __launch_bounds__(256) void conv_f2b(
    const float* __restrict__ in, unsigned short* __restrict__ out) {
  size_t i = ((size_t)blockIdx.x * 256 + threadIdx.x) * 4;
  f32x4 v = *(const f32x4*)(in + i);
  ushort4v w;
#pragma unroll
  for (int e = 0; e < 4; ++e) w[e] = f2b(v[e]);
  *(ushort4v*)(out + i) = w;
}

// out[c][r] = bf16(in[r][c]); R,C multiples of 32; grid (R/32, C/32)
__global__ __launch_bounds__(256) void transpose_f2b(
    const float* __restrict__ in, unsigned short* __restrict__ out,
    int R, int C) {
  __shared__ float tile[32][33];
  int r0 = blockIdx.x * 32, c0 = blockIdx.y * 32;
  int tx = threadIdx.x & 31, ty = threadIdx.x >> 5;
#pragma unroll
  for (int i = 0; i < 4; ++i)
    tile[ty + i * 8][tx] = in[(size_t)(r0 + ty + i * 8) * C + c0 + tx];
  __syncthreads();
#pragma unroll
  for (int i = 0; i < 4; ++i)
    out[(size_t)(c0 + ty + i * 8) * R + r0 + tx] = f2b(tile[tx][ty + i * 8]);
}

// ---------------------------------------------------------------------------
// XCD-rectangle decode: 1-D launch of GX * GY * GZ blocks. bid&7 picks an
// XCD-rectangle (assumes round-robin bid%8 -> XCD; if wrong, perf-neutral).
// Rectangle = RX row-blocks x RG group-ids (g = y + GY*z), g varies fastest.
// Row order is STAGGERED per g-rect so split-K atomic targets of the same
// output tile are never RMW'd from multiple XCDs in lockstep.
// ---------------------------------------------------------------------------
template <int GX, int GY, int GZ, int RX, int RG>
DEVFN void rect_decode(int bid, int& x, int& y, int& z) {
  constexpr int NRG = (GY * GZ) / RG;   // rectangles along g
  const int xcd = bid & 7;
  const int rr = bid >> 3;              // [0, RX*RG)
  const int rgx = xcd % NRG, rxx = xcd / NRG;
  const int gl = rr % RG;
  int xl = rr / RG;
  xl = (xl + rgx * (RX / NRG)) % RX;    // stagger rows across g-rects
  const int g = rgx * RG + gl;
  x = rxx * RX + xl;
  y = g % GY;
  z = g / GY;
}

// ---------------------------------------------------------------------------
// gemm_bt2: C[M,N] = epi(alpha * A[M,K] . B[N,K]^T + bias)  both bf16 K-major.
// 128x256 tile, BK=64, 256 threads (4 waves, 1M x 4N, 128x64 out each).
// TRIPLE-buffered global_load_lds staging + XOR-swizzle (conflict-free):
// iter t stages tile t+2, so tile t's loads were issued TWO full iterations
// (~2000+ cyc) before their first read -> HBM-latency-proof pipeline depth.
// Counted vmcnt never drains mid-loop: after issuing stage(t+2) (12 loads/
// thread), vmcnt(24) = "t+1's 12 + t+2's 12 may remain in flight, everything
// older (= tile t) landed". Tail peel: vmcnt(12) at t=nt-2, vmcnt(0) at last.
// Write-safety (same argument as proven 2-buf version): buf[(t+2)%3] holds
// tile t-1, whose reads completed before iter t-1's end barrier.
// SC=1: C rows shifted per batch. 1-D grid, XCD-rectangle scheduled.
// ---------------------------------------------------------------------------
template <typename CT, bool RELU, int SC, bool BIAS, bool SPLITK,
          int GX, int GY, int GZ, int RX, int RG>
__global__ __launch_bounds__(256, 1) void gemm_bt2(
    const unsigned short* __restrict__ A, const unsigned short* __restrict__ B,
    CT* __restrict__ C, const float* __restrict__ bias,
    int K, int ldc, float alpha) {
  __shared__ unsigned short sA[3][128 * 64];   // 48 KB
  __shared__ unsigned short sB[3][256 * 64];   // 96 KB
  const int tid = threadIdx.x;
  const int wave = tid >> 6, lane = tid & 63;
  int bx, by, bz;
  rect_decode<GX, GY, GZ, RX, RG>((int)blockIdx.x, bx, by, bz);
  const int row0 = bx * 128, col0 = by * 256;
  const unsigned short* Ab = A + (size_t)row0 * K;
  const unsigned short* Bb = B + (size_t)col0 * K;
  const int srow = lane >> 3;
  const int swc = ((lane & 7) ^ srow) * 8;       // pre-swizzled global col
  const int lr = lane & 15;
  const int hi = lane >> 4;
  const int l7 = lane & 7;
  const int ksw0 = (hi ^ l7) * 8;                // swizzled LDS slot, ks=0
  const int ksw1 = ((4 + hi) ^ l7) * 8;          // swizzled LDS slot, ks=1
  const int klen = SPLITK ? (K / GZ) : K;
  const int kbeg = SPLITK ? bz * klen : 0;
  const int nt = klen / 64;
  f32x4 acc[8][4] = {};
  auto stage = [&](int buf, int t) {
    const int k0 = kbeg + t * 64;
    // 48 chunks of 8 rows x 64 cols: 0..15 = A (128 rows), 16..47 = B (256);
    // 12 loads/thread
#pragma unroll
    for (int it = 0; it < 12; ++it) {
      int c = wave * 12 + it;
      if (c < 16) {
        int r = c * 8 + srow;
        load_lds16(Ab + (size_t)r * K + k0 + swc, &sA[buf][c * 512]);
      } else {
        int cb = c - 16;
        int r = cb * 8 + srow;
        load_lds16(Bb + (size_t)r * K + k0 + swc, &sB[buf][cb * 512]);
      }
    }
  };
  stage(0, 0);
  if (nt > 1) stage(1, 1);
  int cur = 0;
  for (int t = 0; t < nt; ++t) {
    if (t + 2 < nt) {
      int b2 = cur + 2; if (b2 >= 3) b2 -= 3;
      stage(b2, t + 2);                          // 12 newer loads in flight
      asm volatile("s_waitcnt vmcnt(24)" ::: "memory");  // tile t landed
    } else if (t + 1 < nt) {
      asm volatile("s_waitcnt vmcnt(12)" ::: "memory");
    } else {
      asm volatile("s_waitcnt vmcnt(0)" ::: "memory");
    }
    __builtin_amdgcn_s_barrier();
    asm volatile("" ::: "memory");
    const unsigned short* cA = &sA[cur][0];
    const unsigned short* cB = &sB[cur][0];
    __builtin_amdgcn_s_setprio(1);
#pragma unroll
    for (int ks = 0; ks < 2; ++ks) {
      const int ko = ks ? ksw1 : ksw0;
      short8 af[8], bfr[4];
#pragma unroll
      for (int i = 0; i < 8; ++i)
        af[i] = *(const short8*)&cA[(i * 16 + lr) * 64 + ko];
#pragma unroll
      for (int j = 0; j < 4; ++j)
        bfr[j] = *(const short8*)&cB[(wave * 64 + j * 16 + lr) * 64 + ko];
#pragma unroll
      for (int i = 0; i < 8; ++i)
#pragma unroll
        for (int j = 0; j < 4; ++j)
          acc[i][j] = __builtin_amdgcn_mfma_f32_16x16x32_bf16(af[i], bfr[j], acc[i][j], 0, 0, 0);
    }
    __builtin_amdgcn_s_setprio(0);
    asm volatile("" ::: "memory");
    __builtin_amdgcn_s_barrier();                // buf reuse safe
    ++cur; if (cur == 3) cur = 0;
  }
  const int rc = (SC == 0) ? 0 : ((row0 >> 10) + 1);
  const int rbase = row0 + rc + (lane >> 4) * 4;
  const int cbase = col0 + wave * 64 + lr;
#pragma unroll
  for (int j = 0; j < 4; ++j) {
    int col = cbase + j * 16;
    float bv = BIAS ? bias[col] : 0.0f;
#pragma unroll
    for (int i = 0; i < 8; ++i) {
#pragma unroll
      for (int r = 0; r < 4; ++r) {
        float vv = acc[i][j][r] * alpha;
        size_t off = (size_t)(rbase + i * 16 + r) * ldc + col;
        if constexpr (SPLITK) {
          atomicAdd((float*)C + off, vv);
        } else {
          vv += bv;
          if (RELU) vv = fmaxf(vv, 0.0f);
          if constexpr (sizeof(CT) == 2) ((unsigned short*)C)[off] = f2b(vv);
          else C[off] = vv;
        }
      }
    }
  }
}

// ---------------------------------------------------------------------------
// gemm_qkv: fused q/k/v projection, ATOMIC-FREE. 384 blocks.
// BM=64, BN=192, split-K=2 (k-halves of 6144). combo = (weight, s):
//   s=0 -> streams bias+partial into qb/kb/vb (shifted rows for k/v;
//          in-batch row 0 keeps the bias prefill, in-batch row 1023 dropped)
//   s=1 -> streams partial into P2[w] (same shift; P2 zero-prefilled)
// then qkv_merge adds P2 into the final buffers. Zero atomics.
// Counted-vmcnt double-buffer pipeline (8 loads/thread per stage).
// ---------------------------------------------------------------------------
__global__ __launch_bounds__(256) void gemm_qkv(
    const unsigned short* __restrict__ A, const unsigned short* __restrict__ Bq,
    const float* __restrict__ bq, const float* __restrict__ bk,
    const float* __restrict__ bv,
    float* __restrict__ qb, float* __restrict__ kb, float* __restrict__ vb,
    float* __restrict__ P2) {
  __shared__ unsigned short sA[2][64 * 64];    // 16 KB
  __shared__ unsigned short sB[2][192 * 64];   // 48 KB
  const int tid = threadIdx.x;
  const int wave = tid >> 6, lane = tid & 63;
  const int bid = (int)blockIdx.x;
  const int xcd = bid & 7;
  const int rr = bid >> 3;                  // [0,48)
  const int grank = xcd * 48 + rr;          // combo-major global rank
  const int combo = grank >> 6;             // [0,6)
  const int row = grank & 63;               // row-block [0,64)
  const int wz = combo >> 1;                // weight: 0=q,1=k,2=v
  const int s = combo & 1;                  // k-half
  const int shift = (wz > 0);
  const unsigned short* B = Bq + (size_t)wz * 192 * 12288;
  const float* bias = (wz == 0) ? bq : (wz == 1 ? bk : bv);
  float* dst = (s == 0) ? ((wz == 0) ? qb : (wz == 1 ? kb : vb))
                        : (P2 + (size_t)wz * 786432);
  const int row0 = row * 64;
  const int ra = (row0 >> 10) + 1;          // z_in view
  const unsigned short* Ab = A + (size_t)(row0 + ra) * 12288;
  const int srow = lane >> 3;
  const int swc = ((lane & 7) ^ srow) * 8;  // pre-swizzled global col
  const int wm = wave & 1, wn = wave >> 1;
  const int lr = lane & 15;
  const int hi = lane >> 4;
  const int l7 = lane & 7;
  const int ksw0 = (hi ^ l7) * 8;
  const int ksw1 = ((4 + hi) ^ l7) * 8;
  const int kbeg = s * 6144;
  f32x4 acc[2][6] = {};
  auto stage = [&](int buf, int t) {
    const int k0 = kbeg + t * 64;
    // 32 chunks of 8 rows: 0..7 = A (64 rows), 8..31 = B; 8 loads/thread
#pragma unroll
    for (int it = 0; it < 8; ++it) {
      int c = wave * 8 + it;
      if (c < 8) {
        int r = c * 8 + srow;
        load_lds16(Ab + (size_t)r * 12288 + k0 + swc, &sA[buf][c * 512]);
      } else {
        int cb = c - 8;
        int r = cb * 8 + srow;
        load_lds16(B + (size_t)r * 12288 + k0 + swc, &sB[buf][cb * 512]);
      }
    }
  };
  stage(0, 0);
  for (int t = 0; t < 96; ++t) {
    const int cur = t & 1;
    if (t + 1 < 96) {
      stage(cur ^ 1, t + 1);
      asm volatile("s_waitcnt vmcnt(8)" ::: "memory");
    } else {
      asm volatile("s_waitcnt vmcnt(0)" ::: "memory");
    }
    __builtin_amdgcn_s_barrier();
    asm volatile("" ::: "memory");
    const unsigned short* cA = &sA[cur][0];
    const unsigned short* cB = &sB[cur][0];
#pragma unroll
    for (int ks = 0; ks < 2; ++ks) {
      const int ko = ks ? ksw1 : ksw0;
      short8 af[2], bfr[6];
#pragma unroll
      for (int i = 0; i < 2; ++i)
        af[i] = *(const short8*)&cA[(wm * 32 + i * 16 + lr) * 64 + ko];
#pragma unroll
      for (int j = 0; j < 6; ++j)
        bfr[j] = *(const short8*)&cB[(wn * 96 + j * 16 + lr) * 64 + ko];
#pragma unroll
      for (int i = 0; i < 2; ++i)
#pragma unroll
        for (int j = 0; j < 6; ++j)
          acc[i][j] = __builtin_amdgcn_mfma_f32_16x16x32_bf16(af[i], bfr[j], acc[i][j], 0, 0, 0);
    }
    asm volatile("" ::: "memory");
    __builtin_amdgcn_s_barrier();
  }
  const int rbase = row0 + wm * 32 + (lane >> 4) * 4;
  const int cbase = wn * 96 + lr;
#pragma unroll
  for (int j = 0; j < 6; ++j) {
    int col = cbase + j * 16;
    float bvv = (s == 0) ? bias[col] : 0.0f;
#pragma unroll
    for (int i = 0; i < 2; ++i)
#pragma unroll
      for (int r = 0; r < 4; ++r) {
        int rw = rbase + i * 16 + r;
        if (shift) {
          if ((rw & 1023) == 1023) continue;  // dropped (next batch row 0 = bias)
          rw += 1;
        }
        dst[(size_t)rw * 192 + col] = acc[i][j][r] + bvv;
      }
  }
}

// dst[w] += P2[w] elementwise over 3 x 4096 x 192 floats
__global__ __launch_bounds__(256) void qkv_merge(
    const float* __restrict__ P2, float* __restrict__ qb,
    float* __restrict__ kb, float* __restrict__ vb) {
  size_t i = ((size_t)blockIdx.x * 256 + threadIdx.x) * 4;
  const int plane = (int)(i / 786432);
  const size_t o = i - (size_t)plane * 786432;
  float* dst = plane == 0 ? qb : (plane == 1 ? kb : vb);
  f32x4 a = *(const f32x4*)(P2 + i);
  f32x4 b = *(const f32x4*)(dst + o);
#pragma unroll
  for (int e = 0; e < 4; ++e) b[e] += a[e];
  *(f32x4*)(dst + o) = b;
}

// ---------------------------------------------------------------------------
// Attention pass 1, BLOCK-COOPERATIVE: block = (b, h, q-quad j, chunk c).
// 4 waves handle qgroups 4j..4j+3 against ONE 128-row K/V chunk staged in
// LDS (24 KB). All qgroups of quad j have g8 = j>>1, so quad j needs chunks
// 0..(j>>1): 72 block-tasks per (b,h) via off(j) = a^2+a+(j&1)(a+1), a=j>>1.
// Grid 2304, XCD-local on bh (xcd owns bh in [4*xcd, 4*xcd+4)).
// Partials P[task][wave*16+qi] = {m, l, ov[24]} stride 28 floats.
// ---------------------------------------------------------------------------
__global__ __launch_bounds__(256) void attn_pass1(
    const float* __restrict__ q, const float* __restrict__ k,
    const float* __restrict__ v, float* __restrict__ P) {
  __shared__ float sK[128 * 24];   // 12 KB
  __shared__ float sV[128 * 24];   // 12 KB
  const int tid = threadIdx.x;
  const int wave = tid >> 6, lane = tid & 63;
  const int xcd = (int)blockIdx.x & 7;
  const int r0 = (int)blockIdx.x >> 3;        // [0,288)
  const int bh = xcd * 4 + r0 / 72;
  const int t = r0 % 72;                      // [0,72)
  const int b = bh >> 3, h = bh & 7;
  // decode t -> (quad jq, chunk c)
  int jq = 0;
  while (true) {
    int jn = jq + 1;
    int a2 = jn >> 1;
    int offn = a2 * a2 + a2 + (jn & 1) * (a2 + 1);
    if (jn < 16 && offn <= t) jq = jn; else break;
  }
  const int aq = jq >> 1;
  const int offj = aq * aq + aq + (jq & 1) * (aq + 1);
  const int c = t - offj;                     // chunk in [0, jq>>1]
  const int qg = jq * 4 + wave;               // this wave's qgroup
  const int qi = lane & 15, ks = lane >> 4;
  const int qpos = qg * 16 + qi;
  const int n = b * 1024 + qpos;
  const int task = bh * 72 + t;
  // stage chunk K/V (128 rows x 24 floats) into LDS; fully coalesced f32x4
  {
    const float* kg = k + (size_t)(b * 1024 + c * 128) * 192 + h * 24;
    const float* vg = v + (size_t)(b * 1024 + c * 128) * 192 + h * 24;
#pragma unroll
    for (int i = 0; i < 3; ++i) {
      int idx = tid + i * 256;               // [0,768)
      int row = idx / 6, seg = idx - row * 6;
      *(f32x4*)&sK[row * 24 + seg * 4] =
          *(const f32x4*)(kg + (size_t)row * 192 + seg * 4);
      *(f32x4*)&sV[row * 24 + seg * 4] =
          *(const f32x4*)(vg + (size_t)row * 192 + seg * 4);
    }
  }
  const float scale = 0.20412414523193154f;  // 1/sqrt(24)
  float qv[24];
  const float* qr = q + (size_t)n * 192 + h * 24;
#pragma unroll
  for (int d = 0; d < 24; ++d) qv[d] = qr[d] * scale;
  __syncthreads();
  float m = -1e30f, l = 0.0f, ov[24] = {};
  const int kb0 = c * 128;
  const int kend = min(qpos, kb0 + 127);
  for (int kp = kb0 + ks; kp <= kend; kp += 4) {
    const f32x4* kr = (const f32x4*)&sK[(kp - kb0) * 24];
    float s0 = 0.0f, s1 = 0.0f, s2 = 0.0f;
#pragma unroll
    for (int j = 0; j < 2; ++j) {
      f32x4 k0 = kr[j * 3 + 0], k1 = kr[j * 3 + 1], k2 = kr[j * 3 + 2];
#pragma unroll
      for (int e = 0; e < 4; ++e) {
        s0 += qv[(j * 3 + 0) * 4 + e] * k0[e];
        s1 += qv[(j * 3 + 1) * 4 + e] * k1[e];
        s2 += qv[(j * 3 + 2) * 4 + e] * k2[e];
      }
    }
    float s = s0 + s1 + s2;
    float mn = fmaxf(m, s);
    float corr = __expf(m - mn);
    float p = __expf(s - mn);
    const f32x4* vr = (const f32x4*)&sV[(kp - kb0) * 24];
    l = l * corr + p;
#pragma unroll
    for (int j = 0; j < 6; ++j) {
      f32x4 vvv = vr[j];
#pragma unroll
      for (int e = 0; e < 4; ++e) ov[j * 4 + e] = ov[j * 4 + e] * corr + p * vvv[e];
    }
    m = mn;
  }
  // merge the 4 k-slices (lanes qi, qi+16, qi+32, qi+48)
#pragma unroll
  for (int off = 16; off < 64; off <<= 1) {
    float m2 = __shfl_xor(m, off);
    float l2 = __shfl_xor(l, off);
    float mn = fmaxf(m, m2);
    float c1 = __expf(m - mn), c2 = __expf(m2 - mn);
    l = l * c1 + l2 * c2;
#pragma unroll
    for (int d = 0; d < 24; ++d) {
      float o2 = __shfl_xor(ov[d], off);
      ov[d] = ov[d] * c1 + o2 * c2;
    }
    m = mn;
  }
  if (ks == 0) {
    float* pr = P + ((size_t)task * 64 + wave * 16 + qi) * 28;
    pr[0] = m;
    pr[1] = l;
#pragma unroll
    for (int d = 0; d < 24; ++d) pr[2 + d] = ov[d];
  }
}

__global__ __launch_bounds__(192) void attn_merge(
    const float* __restrict__ P, unsigned short* __restrict__ o) {
  const int n = blockIdx.x;            // 0..4095
  const int tid = threadIdx.x;
  const int h = tid / 24, d = tid - h * 24;
  const int b = n >> 10, qpos = n & 1023;
  const int qg = qpos >> 4, qi = qpos & 15;
  const int j = qg >> 2, w = qg & 3;
  const int a = j >> 1;                // == g8
  const int nch = a + 1;
  const int offj = a * a + a + (j & 1) * (a + 1);
  const int bh = b * 8 + h;
  const int base = bh * 72 + offj;
  float M = -1e30f;
  for (int cc = 0; cc < nch; ++cc)
    M = fmaxf(M, P[((size_t)(base + cc) * 64 + w * 16 + qi) * 28]);
  float L = 0.0f, OV = 0.0f;
  for (int cc = 0; cc < nch; ++cc) {
    const float* pr = P + ((size_t)(base + cc) * 64 + w * 16 + qi) * 28;
    float wgt = __expf(pr[0] - M);
    L += pr[1] * wgt;
    OV += pr[2 + d] * wgt;
  }
  o[(size_t)n * 192 + h * 24 + d] = f2b(OV / L);
}

// per-row: p = dot(Dz,x)/(||Dz||+eps)^2 ; x -= p*Dz ; xb = bf16(x)
__global__ __launch_bounds__(256) void proj_update(
    const float* __restrict__ Dz, float* __restrict__ x,
    unsigned short* __restrict__ xb) {
  const int n = blockIdx.x;
  const int tid = threadIdx.x;
  const float* dz = Dz + (size_t)n * 768;
  float* xr = x + (size_t)n * 768;
  float dot = 0.0f, s2 = 0.0f;
  for (int i = tid; i < 768; i += 256) {
    float a = dz[i], c = xr[i];
    dot += a * c;
    s2 += a * a;
  }
#pragma unroll
  for (int o2 = 32; o2; o2 >>= 1) {
    dot += __shfl_down(dot, o2);
    s2 += __shfl_down(s2, o2);
  }
  __shared__ float sd[4], ss[4], sp;
  const int wave = tid >> 6, lane = tid & 63;
  if (lane == 0) { sd[wave] = dot; ss[wave] = s2; }
  __syncthreads();
  if (tid == 0) {
    float Dd = sd[0] + sd[1] + sd[2] + sd[3];
    float S = ss[0] + ss[1] + ss[2] + ss[3];
    float nrm = sqrtf(S) + 1e-6f;
    sp = Dd / (nrm * nrm);
  }
  __syncthreads();
  float p = sp;
  for (int i = tid; i < 768; i += 256) {
    float nx = xr[i] - p * dz[i];
    xr[i] = nx;
    xb[(size_t)n * 768 + i] = f2b(nx);
  }
}

DEVFN int sanitize(int v) { return (v & 0x8000) ? 0 : v; }  // -0/neg codes -> 0

// top-32 of z_novel row (bf16 codes nonneg => int order = value order);
// emits 32 (idx,val) pairs per row (slot order arbitrary).
__global__ __launch_bounds__(256) void topk_rows(
    const unsigned short* __restrict__ zbuf, int* __restrict__ idxo,
    float* __restrict__ valo) {
  const int n = blockIdx.x;
  const int b = n >> 10;
  const int tid = threadIdx.x;
  const int wave = tid >> 6, lane = tid & 63;
  const uint4v* zr = (const uint4v*)(zbuf + (size_t)(n + b + 1) * 12288);
  uint4v pk[6];
#pragma unroll
  for (int j = 0; j < 6; ++j) pk[j] = zr[tid * 6 + j];
  __shared__ int swsum[4];
  __shared__ int seq[256];
  __shared__ int spcnt;
  int lo = 0, hi = 0x7F7F;
  while (lo < hi) {
    int mid = (lo + hi) >> 1;
    int c = 0;
#pragma unroll
    for (int j = 0; j < 6; ++j)
#pragma unroll
      for (int e = 0; e < 4; ++e) {
        unsigned int u = pk[j][e];
        c += (sanitize((int)(u & 0xffffu)) > mid) + (sanitize((int)(u >> 16)) > mid);
      }
#pragma unroll
    for (int o2 = 32; o2; o2 >>= 1) c += __shfl_down(c, o2);
    if (lane == 0) swsum[wave] = c;
    __syncthreads();
    int total = swsum[0] + swsum[1] + swsum[2] + swsum[3];
    __syncthreads();
    if (total < 32) hi = mid; else lo = mid + 1;
  }
  const int T = lo;
  int cgt = 0, ceq = 0;
#pragma unroll
  for (int j = 0; j < 6; ++j)
#pragma unroll
    for (int e = 0; e < 4; ++e) {
      unsigned int u = pk[j][e];
      int v0 = sanitize((int)(u & 0xffffu)), v1 = sanitize((int)(u >> 16));
      cgt += (v0 > T) + (v1 > T);
      ceq += (v0 == T) + (v1 == T);
    }
  int cg = cgt;
#pragma unroll
  for (int o2 = 32; o2; o2 >>= 1) cg += __shfl_down(cg, o2);
  if (lane == 0) swsum[wave] = cg;
  seq[tid] = ceq;
  if (tid == 0) spcnt = 0;
  __syncthreads();
  const int total_gt = swsum[0] + swsum[1] + swsum[2] + swsum[3];
  for (int o2 = 1; o2 < 256; o2 <<= 1) {
    int vv = (tid >= o2) ? seq[tid - o2] : 0;
    __syncthreads();
    seq[tid] += vv;
    __syncthreads();
  }
  const int quota = 32 - total_gt;
  int rank = seq[tid] - ceq;
  int* irow = idxo + (size_t)n * 32;
  float* vrow = valo + (size_t)n * 32;
#pragma unroll
  for (int j = 0; j < 6; ++j)
#pragma unroll
    for (int e = 0; e < 4; ++e) {
      unsigned int u = pk[j][e];
#pragma unroll
      for (int hf = 0; hf < 2; ++hf) {
        int v = sanitize(hf ? (int)(u >> 16) : (int)(u & 0xffffu));
        bool kp = false;
        if (v > T) kp = true;
        else if (v == T) { if (rank < quota) kp = true; ++rank; }
        if (kp) {
          int pos = atomicAdd(&spcnt, 1);
          irow[pos] = tid * 48 + j * 8 + e * 2 + hf;
          vrow[pos] = b2f((unsigned short)v);
        }
      }
    }
}

// out = x_input - x_final + sum_j val_j * D[idx_j,:]   (f32 in, f32 out)
__global__ __launch_bounds__(256) void sparse_recons(
    const int* __restrict__ idxo, const float* __restrict__ valo,
    const float* __restrict__ x, const float* __restrict__ xin,
    const float* __restrict__ D, float* __restrict__ out) {
  const int n = blockIdx.x;
  const int t = threadIdx.x;
  __shared__ int sidx[32];
  __shared__ float sval[32];
  if (t < 32) { sidx[t] = idxo[(size_t)n * 32 + t]; sval[t] = valo[(size_t)n * 32 + t]; }
  __syncthreads();
  float acc[3];
#pragma unroll
  for (int u = 0; u < 3; ++u) {
    size_t i = (size_t)n * 768 + t + u * 256;
    acc[u] = xin[i] - x[i];
  }
  for (int j = 0; j < 32; ++j) {
    size_t base = (size_t)sidx[j] * 768;
    float vj = sval[j];
#pragma unroll
    for (int u = 0; u < 3; ++u) acc[u] += vj * D[base + t + u * 256];
  }
#pragma unroll
  for (int u = 0; u < 3; ++u) out[(size_t)n * 768 + t + u * 256] = acc[u];
}

// ===========================================================================
extern "C" void kernel_launch(void* const* d_in, const int* in_sizes, int n_in,
                              void* d_out, int out_size, void* d_ws, size_t ws_size,
                              hipStream_t stream) {
  (void)in_sizes; (void)n_in;
  const float* xin  = (const float*)d_in[0];
  const float* D    = (const float*)d_in[1];
  const float* bvec = (const float*)d_in[2];
  const float* Wq   = (const float*)d_in[3];
  const float* bq   = (const float*)d_in[4];
  const float* Wk   = (const float*)d_in[5];
  const float* bk   = (const float*)d_in[6];
  const float* Wv   = (const float*)d_in[7];
  const float* bv   = (const float*)d_in[8];
  const float* Wo   = (const float*)d_in[9];
  const float* bo   = (const float*)d_in[10];
  const float LAM = 1.0f / 3072.0f;

  char* ws = (char*)d_ws;
  size_t off = 0;
  auto alloc = [&](size_t bytes) {
    void* p = ws + off;
    off += (bytes + 255) & ~(size_t)255;
    return p;
  };
  unsigned short* zbuf = (unsigned short*)alloc((size_t)4 * 1025 * 12288 * 2);
  unsigned short* zpred_ = zbuf;  // alias: lifetimes disjoint
  float* attnP = (float*)zbuf;    // alias: partials live between qkv and Wo GEMMs
  float* x           = (float*)alloc((size_t)4096 * 768 * 4);
  unsigned short* xb = (unsigned short*)alloc((size_t)4096 * 768 * 2);
  float* qb  = (float*)alloc((size_t)4096 * 192 * 4);
  float* kb  = (float*)alloc((size_t)4096 * 192 * 4);
  float* vb  = (float*)alloc((size_t)4096 * 192 * 4);
  unsigned short* ob = (unsigned short*)alloc((size_t)4096 * 192 * 2);
  float* Dz  = (float*)alloc((size_t)4096 * 768 * 4);
  int* idxo  = (int*)alloc((size_t)4096 * 32 * 4);
  float* valo = (float*)alloc((size_t)4096 * 32 * 4);
  const size_t WQKV = (size_t)192 * 12288;   // per (layer, weight)
  unsigned short* WqkvT = (unsigned short*)alloc((size_t)6 * WQKV * 2);
  unsigned short* WoT   = (unsigned short*)alloc((size_t)2 * 12288 * 192 * 2);
  unsigned short* Dbt   = (unsigned short*)alloc((size_t)12288 * 768 * 2);
  unsigned short* Dt    = (unsigned short*)alloc((size_t)768 * 12288 * 2);
  const size_t NEED = off;  // ~219.8 MB (confirmed fitting in R5/R6)
  // qkv split-1 partials alias the (dead at qkv time) Dz buffer: 9.44 MB <= 12.6 MB
  float* P2 = Dz;

  if (ws_size < NEED) {  // safety net (should never fire)
    fill_out_zero<<<(out_size + 255) / 256, 256, 0, stream>>>((float*)d_out, out_size);
    return;
  }

  init_x<<<12288, 256, 0, stream>>>(xin, bvec, x, xb);
  conv_f2b<<<9216, 256, 0, stream>>>(D, Dbt);
  transpose_f2b<<<dim3(384, 24), 256, 0, stream>>>(D, Dt, 12288, 768);
  for (int l = 0; l < 2; ++l) {
    transpose_f2b<<<dim3(384, 6), 256, 0, stream>>>(
        Wq + (size_t)l * 12288 * 192, WqkvT + (size_t)(l * 3 + 0) * WQKV, 12288, 192);
    transpose_f2b<<<dim3(384, 6), 256, 0, stream>>>(
        Wk + (size_t)l * 12288 * 192, WqkvT + (size_t)(l * 3 + 1) * WQKV, 12288, 192);
    transpose_f2b<<<dim3(384, 6), 256, 0, stream>>>(
        Wv + (size_t)l * 12288 * 192, WqkvT + (size_t)(l * 3 + 2) * WQKV, 12288, 192);
    transpose_f2b<<<dim3(6, 384), 256, 0, stream>>>(
        Wo + (size_t)l * 192 * 12288, WoT + (size_t)l * 12288 * 192, 192, 12288);
  }

  for (int l = 0; l < 2; ++l) {
    // z_in = relu(LAM * x @ D^T) -> zbuf shifted rows [b*1025+1 ..]
    // 128x256 tile: grid 32x48 -> 1-D 1536, XCD-rect 32x x 6y (B 2.3 MB/XCD)
    gemm_bt2<unsigned short, true, 1, false, false, 32, 48, 1, 32, 6>
        <<<1536, 256, 0, stream>>>(xb, Dbt, zbuf, nullptr, 768, 12288, LAM);
    // k/v row-0 prefill (= zero-context bias row); qb fully written by qkv s=0.
    fill_bias<<<3072, 256, 0, stream>>>(kb, bk + (size_t)l * 192, 192);
    fill_bias<<<3072, 256, 0, stream>>>(vb, bv + (size_t)l * 192, 192);
    // P2 zero-prefill (rows (b,0) of k/v planes must read as 0 in the merge)
    fill_bias<<<9216, 256, 0, stream>>>(P2, nullptr, 192);
    // atomic-free fused q/k/v: split 0 -> final bufs, split 1 -> P2; merge.
    gemm_qkv<<<384, 256, 0, stream>>>(
        zbuf, WqkvT + (size_t)(l * 3) * WQKV,
        bq + (size_t)l * 192, bk + (size_t)l * 192, bv + (size_t)l * 192,
        qb, kb, vb, P2);
    qkv_merge<<<2304, 256, 0, stream>>>(P2, qb, kb, vb);
    // Attention (z_in in zbuf is dead now; attnP scratch aliases it)
    attn_pass1<<<2304, 256, 0, stream>>>(qb, kb, vb, attnP);
    attn_merge<<<4096, 192, 0, stream>>>(attnP, ob);
    // z_pred_ = relu(o @ Wo + bo) -> zpred_ (aliases zbuf; attnP dead)
    gemm_bt2<unsigned short, true, 0, true, false, 32, 48, 1, 32, 6>
        <<<1536, 256, 0, stream>>>(
        ob, WoT + (size_t)l * 12288 * 192, zpred_, bo + (size_t)l * 12288, 192, 12288, 1.0f);
    // Dz = z_pred_ @ D  (128x256 tile, split-K=4 -> 384 blocks)
    fill_bias<<<12288, 256, 0, stream>>>(Dz, nullptr, 768);
    gemm_bt2<float, false, 0, false, true, 32, 3, 4, 8, 6>
        <<<384, 256, 0, stream>>>(zpred_, Dt, Dz, nullptr, 12288, 768, 1.0f);
    proj_update<<<4096, 256, 0, stream>>>(Dz, x, xb);
  }
  // z_novel = relu(LAM * x @ D^T) -> zbuf shifted rows
  gemm_bt2<unsigned short, true, 1, false, false, 32, 48, 1, 32, 6>
      <<<1536, 256, 0, stream>>>(xb, Dbt, zbuf, nullptr, 768, 12288, LAM);
  topk_rows<<<4096, 256, 0, stream>>>(zbuf, idxo, valo);
  sparse_recons<<<4096, 256, 0, stream>>>(idxo, valo, x, xin, D, (float*)d_out);
}

// Round 13
// 1303.520 us; speedup vs baseline: 1.0643x; 1.0643x over previous
//
#include <hip/hip_runtime.h>
#include <hip/hip_bf16.h>

typedef __attribute__((ext_vector_type(4))) float f32x4;
typedef __attribute__((ext_vector_type(8))) short short8;
typedef __attribute__((ext_vector_type(8))) unsigned short ushort8;
typedef __attribute__((ext_vector_type(4))) unsigned short ushort4v;
typedef __attribute__((ext_vector_type(4))) unsigned int uint4v;

#define DEVFN __device__ __forceinline__

DEVFN float b2f(unsigned short u) { return __uint_as_float(((unsigned)u) << 16); }
DEVFN unsigned short f2b(float f) {
  __hip_bfloat16 h = __float2bfloat16(f);
  return __builtin_bit_cast(unsigned short, h);
}

DEVFN void load_lds16(const void* g, void* l) {
  __builtin_amdgcn_global_load_lds(
      (const __attribute__((address_space(1))) unsigned int*)g,
      (__attribute__((address_space(3))) unsigned int*)l, 16, 0, 0);
}

// ===========================================================================

__global__ void fill_out_zero(float* o, int n) {
  int i = blockIdx.x * 256 + threadIdx.x;
  if (i < n) o[i] = 0.0f;
}

__global__ __launch_bounds__(256) void init_x(
    const float* __restrict__ xin, const float* __restrict__ bvec,
    float* __restrict__ x, unsigned short* __restrict__ xb) {
  size_t i = (size_t)blockIdx.x * 256 + threadIdx.x;
  int col = (int)(i % 768);
  float v = xin[i] - bvec[col];
  x[i] = v;
  xb[i] = f2b(v);
}

// buf[i] = bias[i % ld] (or 0 if bias null)
__global__ __launch_bounds__(256) void fill_bias(
    float* __restrict__ buf, const float* __restrict__ bias, int ld) {
  size_t i = (size_t)blockIdx.x * 256 + threadIdx.x;
  buf[i] = bias ? bias[(int)(i % ld)] : 0.0f;
}

// f32 -> bf16 straight convert, 4 elems/thread (n must be /1024)
__global__ __launch_bounds__(256) void conv_f2b(
    const float* __restrict__ in, unsigned short* __restrict__ out) {
  size_t i = ((size_t)blockIdx.x * 256 + threadIdx.x) * 4;
  f32x4 v = *(const f32x4*)(in + i);
  ushort4v w;
#pragma unroll
  for (int e = 0; e < 4; ++e) w[e] = f2b(v[e]);
  *(ushort4v*)(out + i) = w;
}

// out[c][r] = bf16(in[r][c]); R,C multiples of 32; grid (R/32, C/32)
__global__ __launch_bounds__(256) void transpose_f2b(
    const float* __restrict__ in, unsigned short* __restrict__ out,
    int R, int C) {
  __shared__ float tile[32][33];
  int r0 = blockIdx.x * 32, c0 = blockIdx.y * 32;
  int tx = threadIdx.x & 31, ty = threadIdx.x >> 5;
#pragma unroll
  for (int i = 0; i < 4; ++i)
    tile[ty + i * 8][tx] = in[(size_t)(r0 + ty + i * 8) * C + c0 + tx];
  __syncthreads();
#pragma unroll
  for (int i = 0; i < 4; ++i)
    out[(size_t)(c0 + ty + i * 8) * R + r0 + tx] = f2b(tile[tx][ty + i * 8]);
}

// ---------------------------------------------------------------------------
// XCD-rectangle decode: 1-D launch of GX * GY * GZ blocks. bid&7 picks an
// XCD-rectangle (assumes round-robin bid%8 -> XCD; if wrong, perf-neutral).
// Rectangle = RX row-blocks x RG group-ids (g = y + GY*z), g varies fastest.
// Row order is STAGGERED per g-rect so split-K atomic targets of the same
// output tile are never RMW'd from multiple XCDs in lockstep.
// ---------------------------------------------------------------------------
template <int GX, int GY, int GZ, int RX, int RG>
DEVFN void rect_decode(int bid, int& x, int& y, int& z) {
  constexpr int NRG = (GY * GZ) / RG;   // rectangles along g
  const int xcd = bid & 7;
  const int rr = bid >> 3;              // [0, RX*RG)
  const int rgx = xcd % NRG, rxx = xcd / NRG;
  const int gl = rr % RG;
  int xl = rr / RG;
  xl = (xl + rgx * (RX / NRG)) % RX;    // stagger rows across g-rects
  const int g = rgx * RG + gl;
  x = rxx * RX + xl;
  y = g % GY;
  z = g / GY;
}

// ---------------------------------------------------------------------------
// gemm_bt2: C[M,N] = epi(alpha * A[M,K] . B[N,K]^T + bias)  both bf16 K-major.
// 256x256 tile, BK=64, 512 threads (8 waves, 2M x 4N, 128x64 out each).
// Double-buffered global_load_lds staging + XOR-swizzle (conflict-free).
// T4 counted-vmcnt pipeline: each thread issues exactly 8 loads per stage;
// after issuing stage(t+1), s_waitcnt vmcnt(8) waits only for stage(t)'s
// loads; RAW s_barrier (no vmcnt(0) drain) -> stage(t+1) stays in flight
// across the barrier and lands under compute(t). Two raw barriers/iter.
// T5 setprio around the MFMA cluster (counted-vmcnt gives wave role
// diversity -> scheduler has something to arbitrate).
// SC=1: C rows shifted per batch. 1-D grid, XCD-rectangle scheduled.
// ---------------------------------------------------------------------------
template <typename CT, bool RELU, int SC, bool BIAS, bool SPLITK,
          int GX, int GY, int GZ, int RX, int RG>
__global__ __launch_bounds__(512, 2) void gemm_bt2(
    const unsigned short* __restrict__ A, const unsigned short* __restrict__ B,
    CT* __restrict__ C, const float* __restrict__ bias,
    int K, int ldc, float alpha) {
  __shared__ unsigned short sA[2][256 * 64];   // 64 KB
  __shared__ unsigned short sB[2][256 * 64];   // 64 KB
  const int tid = threadIdx.x;
  const int wave = tid >> 6, lane = tid & 63;
  int bx, by, bz;
  rect_decode<GX, GY, GZ, RX, RG>((int)blockIdx.x, bx, by, bz);
  const int row0 = bx * 256, col0 = by * 256;
  const unsigned short* Ab = A + (size_t)row0 * K;
  const unsigned short* Bb = B + (size_t)col0 * K;
  const int srow = lane >> 3;
  const int swc = ((lane & 7) ^ srow) * 8;       // pre-swizzled global col
  const int wm = wave & 1, wn = wave >> 1;       // 2 x 4 wave grid
  const int lr = lane & 15;
  const int hi = lane >> 4;
  const int l7 = lane & 7;
  const int ksw0 = (hi ^ l7) * 8;                // swizzled LDS slot, ks=0
  const int ksw1 = ((4 + hi) ^ l7) * 8;          // swizzled LDS slot, ks=1
  const int klen = SPLITK ? (K / GZ) : K;
  const int kbeg = SPLITK ? bz * klen : 0;
  const int nt = klen / 64;
  f32x4 acc[8][4] = {};
  auto stage = [&](int buf, int t) {
    const int k0 = kbeg + t * 64;
    // 64 chunks of 8 rows x 64 cols: 0..31 = A, 32..63 = B; 8 loads/thread
#pragma unroll
    for (int it = 0; it < 8; ++it) {
      int c = wave * 8 + it;
      if (c < 32) {
        int r = c * 8 + srow;
        load_lds16(Ab + (size_t)r * K + k0 + swc, &sA[buf][c * 512]);
      } else {
        int cb = c - 32;
        int r = cb * 8 + srow;
        load_lds16(Bb + (size_t)r * K + k0 + swc, &sB[buf][cb * 512]);
      }
    }
  };
  stage(0, 0);
  for (int t = 0; t < nt; ++t) {
    const int cur = t & 1;
    if (t + 1 < nt) {
      stage(cur ^ 1, t + 1);                       // 8 newer loads in flight
      asm volatile("s_waitcnt vmcnt(8)" ::: "memory");  // stage(t) landed
    } else {
      asm volatile("s_waitcnt vmcnt(0)" ::: "memory");
    }
    __builtin_amdgcn_s_barrier();                  // raw: no vmem drain
    asm volatile("" ::: "memory");
    const unsigned short* cA = &sA[cur][0];
    const unsigned short* cB = &sB[cur][0];
    __builtin_amdgcn_s_setprio(1);
#pragma unroll
    for (int ks = 0; ks < 2; ++ks) {
      const int ko = ks ? ksw1 : ksw0;
      short8 af[8], bfr[4];
#pragma unroll
      for (int i = 0; i < 8; ++i)
        af[i] = *(const short8*)&cA[(wm * 128 + i * 16 + lr) * 64 + ko];
#pragma unroll
      for (int j = 0; j < 4; ++j)
        bfr[j] = *(const short8*)&cB[(wn * 64 + j * 16 + lr) * 64 + ko];
#pragma unroll
      for (int i = 0; i < 8; ++i)
#pragma unroll
        for (int j = 0; j < 4; ++j)
          acc[i][j] = __builtin_amdgcn_mfma_f32_16x16x32_bf16(af[i], bfr[j], acc[i][j], 0, 0, 0);
    }
    __builtin_amdgcn_s_setprio(0);
    asm volatile("" ::: "memory");
    __builtin_amdgcn_s_barrier();                  // buf reuse safe
  }
  const int rc = (SC == 0) ? 0 : ((row0 >> 10) + 1);
  const int rbase = row0 + rc + wm * 128 + (lane >> 4) * 4;
  const int cbase = col0 + wn * 64 + lr;
#pragma unroll
  for (int j = 0; j < 4; ++j) {
    int col = cbase + j * 16;
    float bv = BIAS ? bias[col] : 0.0f;
#pragma unroll
    for (int i = 0; i < 8; ++i) {
#pragma unroll
      for (int r = 0; r < 4; ++r) {
        float vv = acc[i][j][r] * alpha;
        size_t off = (size_t)(rbase + i * 16 + r) * ldc + col;
        if constexpr (SPLITK) {
          atomicAdd((float*)C + off, vv);
        } else {
          vv += bv;
          if (RELU) vv = fmaxf(vv, 0.0f);
          if constexpr (sizeof(CT) == 2) ((unsigned short*)C)[off] = f2b(vv);
          else C[off] = vv;
        }
      }
    }
  }
}

// ---------------------------------------------------------------------------
// gemm_qkv: fused q/k/v projection, ATOMIC-FREE. 384 blocks.
// BM=64, BN=192, split-K=2 (k-halves of 6144). combo = (weight, s):
//   s=0 -> streams bias+partial into qb/kb/vb (shifted rows for k/v;
//          in-batch row 0 keeps the bias prefill, in-batch row 1023 dropped)
//   s=1 -> streams partial into P2[w] (same shift; P2 zero-prefilled)
// then qkv_merge adds P2 into the final buffers. Zero atomics.
// A-LOCALITY remap: combo varies FASTEST within an XCD (combo = rr%6,
// row = xcd*8 + rr/6, bijective over 384) -> the 6 co-resident combos of a
// row-batch read the SAME 1.5 MB A-panel (L2-hit x6) instead of streaming
// 6 disjoint A regions (was 161 MB FETCH).
// Counted-vmcnt double-buffer pipeline (8 loads/thread per stage) + T5.
// ---------------------------------------------------------------------------
__global__ __launch_bounds__(256) void gemm_qkv(
    const unsigned short* __restrict__ A, const unsigned short* __restrict__ Bq,
    const float* __restrict__ bq, const float* __restrict__ bk,
    const float* __restrict__ bv,
    float* __restrict__ qb, float* __restrict__ kb, float* __restrict__ vb,
    float* __restrict__ P2) {
  __shared__ unsigned short sA[2][64 * 64];    // 16 KB
  __shared__ unsigned short sB[2][192 * 64];   // 48 KB
  const int tid = threadIdx.x;
  const int wave = tid >> 6, lane = tid & 63;
  const int bid = (int)blockIdx.x;
  const int xcd = bid & 7;
  const int rr = bid >> 3;                  // [0,48)
  const int combo = rr % 6;                 // combo fastest (A L2 reuse x6)
  const int row = xcd * 8 + rr / 6;         // row-block [0,64)
  const int wz = combo >> 1;                // weight: 0=q,1=k,2=v
  const int s = combo & 1;                  // k-half
  const int shift = (wz > 0);
  const unsigned short* B = Bq + (size_t)wz * 192 * 12288;
  const float* bias = (wz == 0) ? bq : (wz == 1 ? bk : bv);
  float* dst = (s == 0) ? ((wz == 0) ? qb : (wz == 1 ? kb : vb))
                        : (P2 + (size_t)wz * 786432);
  const int row0 = row * 64;
  const int ra = (row0 >> 10) + 1;          // z_in view
  const unsigned short* Ab = A + (size_t)(row0 + ra) * 12288;
  const int srow = lane >> 3;
  const int swc = ((lane & 7) ^ srow) * 8;  // pre-swizzled global col
  const int wm = wave & 1, wn = wave >> 1;
  const int lr = lane & 15;
  const int hi = lane >> 4;
  const int l7 = lane & 7;
  const int ksw0 = (hi ^ l7) * 8;
  const int ksw1 = ((4 + hi) ^ l7) * 8;
  const int kbeg = s * 6144;
  f32x4 acc[2][6] = {};
  auto stage = [&](int buf, int t) {
    const int k0 = kbeg + t * 64;
    // 32 chunks of 8 rows: 0..7 = A (64 rows), 8..31 = B; 8 loads/thread
#pragma unroll
    for (int it = 0; it < 8; ++it) {
      int c = wave * 8 + it;
      if (c < 8) {
        int r = c * 8 + srow;
        load_lds16(Ab + (size_t)r * 12288 + k0 + swc, &sA[buf][c * 512]);
      } else {
        int cb = c - 8;
        int r = cb * 8 + srow;
        load_lds16(B + (size_t)r * 12288 + k0 + swc, &sB[buf][cb * 512]);
      }
    }
  };
  stage(0, 0);
  for (int t = 0; t < 96; ++t) {
    const int cur = t & 1;
    if (t + 1 < 96) {
      stage(cur ^ 1, t + 1);
      asm volatile("s_waitcnt vmcnt(8)" ::: "memory");
    } else {
      asm volatile("s_waitcnt vmcnt(0)" ::: "memory");
    }
    __builtin_amdgcn_s_barrier();
    asm volatile("" ::: "memory");
    const unsigned short* cA = &sA[cur][0];
    const unsigned short* cB = &sB[cur][0];
    __builtin_amdgcn_s_setprio(1);
#pragma unroll
    for (int ks = 0; ks < 2; ++ks) {
      const int ko = ks ? ksw1 : ksw0;
      short8 af[2], bfr[6];
#pragma unroll
      for (int i = 0; i < 2; ++i)
        af[i] = *(const short8*)&cA[(wm * 32 + i * 16 + lr) * 64 + ko];
#pragma unroll
      for (int j = 0; j < 6; ++j)
        bfr[j] = *(const short8*)&cB[(wn * 96 + j * 16 + lr) * 64 + ko];
#pragma unroll
      for (int i = 0; i < 2; ++i)
#pragma unroll
        for (int j = 0; j < 6; ++j)
          acc[i][j] = __builtin_amdgcn_mfma_f32_16x16x32_bf16(af[i], bfr[j], acc[i][j], 0, 0, 0);
    }
    __builtin_amdgcn_s_setprio(0);
    asm volatile("" ::: "memory");
    __builtin_amdgcn_s_barrier();
  }
  const int rbase = row0 + wm * 32 + (lane >> 4) * 4;
  const int cbase = wn * 96 + lr;
#pragma unroll
  for (int j = 0; j < 6; ++j) {
    int col = cbase + j * 16;
    float bvv = (s == 0) ? bias[col] : 0.0f;
#pragma unroll
    for (int i = 0; i < 2; ++i)
#pragma unroll
      for (int r = 0; r < 4; ++r) {
        int rw = rbase + i * 16 + r;
        if (shift) {
          if ((rw & 1023) == 1023) continue;  // dropped (next batch row 0 = bias)
          rw += 1;
        }
        dst[(size_t)rw * 192 + col] = acc[i][j][r] + bvv;
      }
  }
}

// dst[w] += P2[w] elementwise over 3 x 4096 x 192 floats
__global__ __launch_bounds__(256) void qkv_merge(
    const float* __restrict__ P2, float* __restrict__ qb,
    float* __restrict__ kb, float* __restrict__ vb) {
  size_t i = ((size_t)blockIdx.x * 256 + threadIdx.x) * 4;
  const int plane = (int)(i / 786432);
  const size_t o = i - (size_t)plane * 786432;
  float* dst = plane == 0 ? qb : (plane == 1 ? kb : vb);
  f32x4 a = *(const f32x4*)(P2 + i);
  f32x4 b = *(const f32x4*)(dst + o);
#pragma unroll
  for (int e = 0; e < 4; ++e) b[e] += a[e];
  *(f32x4*)(dst + o) = b;
}

// ---------------------------------------------------------------------------
// Attention pass 1, BLOCK-COOPERATIVE: block = (b, h, q-quad j, chunk c).
// 4 waves handle qgroups 4j..4j+3 against ONE 128-row K/V chunk staged in
// LDS (24 KB). All qgroups of quad j have g8 = j>>1, so quad j needs chunks
// 0..(j>>1): 72 block-tasks per (b,h) via off(j) = a^2+a+(j&1)(a+1), a=j>>1.
// Grid 2304, XCD-local on bh (xcd owns bh in [4*xcd, 4*xcd+4)).
// Partials P[task][wave*16+qi] = {m, l, ov[24]} stride 28 floats.
// ---------------------------------------------------------------------------
__global__ __launch_bounds__(256) void attn_pass1(
    const float* __restrict__ q, const float* __restrict__ k,
    const float* __restrict__ v, float* __restrict__ P) {
  __shared__ float sK[128 * 24];   // 12 KB
  __shared__ float sV[128 * 24];   // 12 KB
  const int tid = threadIdx.x;
  const int wave = tid >> 6, lane = tid & 63;
  const int xcd = (int)blockIdx.x & 7;
  const int r0 = (int)blockIdx.x >> 3;        // [0,288)
  const int bh = xcd * 4 + r0 / 72;
  const int t = r0 % 72;                      // [0,72)
  const int b = bh >> 3, h = bh & 7;
  // decode t -> (quad jq, chunk c)
  int jq = 0;
  while (true) {
    int jn = jq + 1;
    int a2 = jn >> 1;
    int offn = a2 * a2 + a2 + (jn & 1) * (a2 + 1);
    if (jn < 16 && offn <= t) jq = jn; else break;
  }
  const int aq = jq >> 1;
  const int offj = aq * aq + aq + (jq & 1) * (aq + 1);
  const int c = t - offj;                     // chunk in [0, jq>>1]
  const int qg = jq * 4 + wave;               // this wave's qgroup
  const int qi = lane & 15, ks = lane >> 4;
  const int qpos = qg * 16 + qi;
  const int n = b * 1024 + qpos;
  const int task = bh * 72 + t;
  // stage chunk K/V (128 rows x 24 floats) into LDS; fully coalesced f32x4
  {
    const float* kg = k + (size_t)(b * 1024 + c * 128) * 192 + h * 24;
    const float* vg = v + (size_t)(b * 1024 + c * 128) * 192 + h * 24;
#pragma unroll
    for (int i = 0; i < 3; ++i) {
      int idx = tid + i * 256;               // [0,768)
      int row = idx / 6, seg = idx - row * 6;
      *(f32x4*)&sK[row * 24 + seg * 4] =
          *(const f32x4*)(kg + (size_t)row * 192 + seg * 4);
      *(f32x4*)&sV[row * 24 + seg * 4] =
          *(const f32x4*)(vg + (size_t)row * 192 + seg * 4);
    }
  }
  const float scale = 0.20412414523193154f;  // 1/sqrt(24)
  float qv[24];
  const float* qr = q + (size_t)n * 192 + h * 24;
#pragma unroll
  for (int d = 0; d < 24; ++d) qv[d] = qr[d] * scale;
  __syncthreads();
  float m = -1e30f, l = 0.0f, ov[24] = {};
  const int kb0 = c * 128;
  const int kend = min(qpos, kb0 + 127);
  for (int kp = kb0 + ks; kp <= kend; kp += 4) {
    const f32x4* kr = (const f32x4*)&sK[(kp - kb0) * 24];
    float s0 = 0.0f, s1 = 0.0f, s2 = 0.0f;
#pragma unroll
    for (int j = 0; j < 2; ++j) {
      f32x4 k0 = kr[j * 3 + 0], k1 = kr[j * 3 + 1], k2 = kr[j * 3 + 2];
#pragma unroll
      for (int e = 0; e < 4; ++e) {
        s0 += qv[(j * 3 + 0) * 4 + e] * k0[e];
        s1 += qv[(j * 3 + 1) * 4 + e] * k1[e];
        s2 += qv[(j * 3 + 2) * 4 + e] * k2[e];
      }
    }
    float s = s0 + s1 + s2;
    float mn = fmaxf(m, s);
    float corr = __expf(m - mn);
    float p = __expf(s - mn);
    const f32x4* vr = (const f32x4*)&sV[(kp - kb0) * 24];
    l = l * corr + p;
#pragma unroll
    for (int j = 0; j < 6; ++j) {
      f32x4 vvv = vr[j];
#pragma unroll
      for (int e = 0; e < 4; ++e) ov[j * 4 + e] = ov[j * 4 + e] * corr + p * vvv[e];
    }
    m = mn;
  }
  // merge the 4 k-slices (lanes qi, qi+16, qi+32, qi+48)
#pragma unroll
  for (int off = 16; off < 64; off <<= 1) {
    float m2 = __shfl_xor(m, off);
    float l2 = __shfl_xor(l, off);
    float mn = fmaxf(m, m2);
    float c1 = __expf(m - mn), c2 = __expf(m2 - mn);
    l = l * c1 + l2 * c2;
#pragma unroll
    for (int d = 0; d < 24; ++d) {
      float o2 = __shfl_xor(ov[d], off);
      ov[d] = ov[d] * c1 + o2 * c2;
    }
    m = mn;
  }
  if (ks == 0) {
    float* pr = P + ((size_t)task * 64 + wave * 16 + qi) * 28;
    pr[0] = m;
    pr[1] = l;
#pragma unroll
    for (int d = 0; d < 24; ++d) pr[2 + d] = ov[d];
  }
}

__global__ __launch_bounds__(192) void attn_merge(
    const float* __restrict__ P, unsigned short* __restrict__ o) {
  const int n = blockIdx.x;            // 0..4095
  const int tid = threadIdx.x;
  const int h = tid / 24, d = tid - h * 24;
  const int b = n >> 10, qpos = n & 1023;
  const int qg = qpos >> 4, qi = qpos & 15;
  const int j = qg >> 2, w = qg & 3;
  const int a = j >> 1;                // == g8
  const int nch = a + 1;
  const int offj = a * a + a + (j & 1) * (a + 1);
  const int bh = b * 8 + h;
  const int base = bh * 72 + offj;
  float M = -1e30f;
  for (int cc = 0; cc < nch; ++cc)
    M = fmaxf(M, P[((size_t)(base + cc) * 64 + w * 16 + qi) * 28]);
  float L = 0.0f, OV = 0.0f;
  for (int cc = 0; cc < nch; ++cc) {
    const float* pr = P + ((size_t)(base + cc) * 64 + w * 16 + qi) * 28;
    float wgt = __expf(pr[0] - M);
    L += pr[1] * wgt;
    OV += pr[2 + d] * wgt;
  }
  o[(size_t)n * 192 + h * 24 + d] = f2b(OV / L);
}

// per-row: p = dot(Dz,x)/(||Dz||+eps)^2 ; x -= p*Dz ; xb = bf16(x)
__global__ __launch_bounds__(256) void proj_update(
    const float* __restrict__ Dz, float* __restrict__ x,
    unsigned short* __restrict__ xb) {
  const int n = blockIdx.x;
  const int tid = threadIdx.x;
  const float* dz = Dz + (size_t)n * 768;
  float* xr = x + (size_t)n * 768;
  float dot = 0.0f, s2 = 0.0f;
  for (int i = tid; i < 768; i += 256) {
    float a = dz[i], c = xr[i];
    dot += a * c;
    s2 += a * a;
  }
#pragma unroll
  for (int o2 = 32; o2; o2 >>= 1) {
    dot += __shfl_down(dot, o2);
    s2 += __shfl_down(s2, o2);
  }
  __shared__ float sd[4], ss[4], sp;
  const int wave = tid >> 6, lane = tid & 63;
  if (lane == 0) { sd[wave] = dot; ss[wave] = s2; }
  __syncthreads();
  if (tid == 0) {
    float Dd = sd[0] + sd[1] + sd[2] + sd[3];
    float S = ss[0] + ss[1] + ss[2] + ss[3];
    float nrm = sqrtf(S) + 1e-6f;
    sp = Dd / (nrm * nrm);
  }
  __syncthreads();
  float p = sp;
  for (int i = tid; i < 768; i += 256) {
    float nx = xr[i] - p * dz[i];
    xr[i] = nx;
    xb[(size_t)n * 768 + i] = f2b(nx);
  }
}

DEVFN int sanitize(int v) { return (v & 0x8000) ? 0 : v; }  // -0/neg codes -> 0

// top-32 of z_novel row (bf16 codes nonneg => int order = value order);
// emits 32 (idx,val) pairs per row (slot order arbitrary).
__global__ __launch_bounds__(256) void topk_rows(
    const unsigned short* __restrict__ zbuf, int* __restrict__ idxo,
    float* __restrict__ valo) {
  const int n = blockIdx.x;
  const int b = n >> 10;
  const int tid = threadIdx.x;
  const int wave = tid >> 6, lane = tid & 63;
  const uint4v* zr = (const uint4v*)(zbuf + (size_t)(n + b + 1) * 12288);
  uint4v pk[6];
#pragma unroll
  for (int j = 0; j < 6; ++j) pk[j] = zr[tid * 6 + j];
  __shared__ int swsum[4];
  __shared__ int seq[256];
  __shared__ int spcnt;
  int lo = 0, hi = 0x7F7F;
  while (lo < hi) {
    int mid = (lo + hi) >> 1;
    int c = 0;
#pragma unroll
    for (int j = 0; j < 6; ++j)
#pragma unroll
      for (int e = 0; e < 4; ++e) {
        unsigned int u = pk[j][e];
        c += (sanitize((int)(u & 0xffffu)) > mid) + (sanitize((int)(u >> 16)) > mid);
      }
#pragma unroll
    for (int o2 = 32; o2; o2 >>= 1) c += __shfl_down(c, o2);
    if (lane == 0) swsum[wave] = c;
    __syncthreads();
    int total = swsum[0] + swsum[1] + swsum[2] + swsum[3];
    __syncthreads();
    if (total < 32) hi = mid; else lo = mid + 1;
  }
  const int T = lo;
  int cgt = 0, ceq = 0;
#pragma unroll
  for (int j = 0; j < 6; ++j)
#pragma unroll
    for (int e = 0; e < 4; ++e) {
      unsigned int u = pk[j][e];
      int v0 = sanitize((int)(u & 0xffffu)), v1 = sanitize((int)(u >> 16));
      cgt += (v0 > T) + (v1 > T);
      ceq += (v0 == T) + (v1 == T);
    }
  int cg = cgt;
#pragma unroll
  for (int o2 = 32; o2; o2 >>= 1) cg += __shfl_down(cg, o2);
  if (lane == 0) swsum[wave] = cg;
  seq[tid] = ceq;
  if (tid == 0) spcnt = 0;
  __syncthreads();
  const int total_gt = swsum[0] + swsum[1] + swsum[2] + swsum[3];
  for (int o2 = 1; o2 < 256; o2 <<= 1) {
    int vv = (tid >= o2) ? seq[tid - o2] : 0;
    __syncthreads();
    seq[tid] += vv;
    __syncthreads();
  }
  const int quota = 32 - total_gt;
  int rank = seq[tid] - ceq;
  int* irow = idxo + (size_t)n * 32;
  float* vrow = valo + (size_t)n * 32;
#pragma unroll
  for (int j = 0; j < 6; ++j)
#pragma unroll
    for (int e = 0; e < 4; ++e) {
      unsigned int u = pk[j][e];
#pragma unroll
      for (int hf = 0; hf < 2; ++hf) {
        int v = sanitize(hf ? (int)(u >> 16) : (int)(u & 0xffffu));
        bool kp = false;
        if (v > T) kp = true;
        else if (v == T) { if (rank < quota) kp = true; ++rank; }
        if (kp) {
          int pos = atomicAdd(&spcnt, 1);
          irow[pos] = tid * 48 + j * 8 + e * 2 + hf;
          vrow[pos] = b2f((unsigned short)v);
        }
      }
    }
}

// out = x_input - x_final + sum_j val_j * D[idx_j,:]   (f32 in, f32 out)
__global__ __launch_bounds__(256) void sparse_recons(
    const int* __restrict__ idxo, const float* __restrict__ valo,
    const float* __restrict__ x, const float* __restrict__ xin,
    const float* __restrict__ D, float* __restrict__ out) {
  const int n = blockIdx.x;
  const int t = threadIdx.x;
  __shared__ int sidx[32];
  __shared__ float sval[32];
  if (t < 32) { sidx[t] = idxo[(size_t)n * 32 + t]; sval[t] = valo[(size_t)n * 32 + t]; }
  __syncthreads();
  float acc[3];
#pragma unroll
  for (int u = 0; u < 3; ++u) {
    size_t i = (size_t)n * 768 + t + u * 256;
    acc[u] = xin[i] - x[i];
  }
  for (int j = 0; j < 32; ++j) {
    size_t base = (size_t)sidx[j] * 768;
    float vj = sval[j];
#pragma unroll
    for (int u = 0; u < 3; ++u) acc[u] += vj * D[base + t + u * 256];
  }
#pragma unroll
  for (int u = 0; u < 3; ++u) out[(size_t)n * 768 + t + u * 256] = acc[u];
}

// ===========================================================================
extern "C" void kernel_launch(void* const* d_in, const int* in_sizes, int n_in,
                              void* d_out, int out_size, void* d_ws, size_t ws_size,
                              hipStream_t stream) {
  (void)in_sizes; (void)n_in;
  const float* xin  = (const float*)d_in[0];
  const float* D    = (const float*)d_in[1];
  const float* bvec = (const float*)d_in[2];
  const float* Wq   = (const float*)d_in[3];
  const float* bq   = (const float*)d_in[4];
  const float* Wk   = (const float*)d_in[5];
  const float* bk   = (const float*)d_in[6];
  const float* Wv   = (const float*)d_in[7];
  const float* bv   = (const float*)d_in[8];
  const float* Wo   = (const float*)d_in[9];
  const float* bo   = (const float*)d_in[10];
  const float LAM = 1.0f / 3072.0f;

  char* ws = (char*)d_ws;
  size_t off = 0;
  auto alloc = [&](size_t bytes) {
    void* p = ws + off;
    off += (bytes + 255) & ~(size_t)255;
    return p;
  };
  unsigned short* zbuf = (unsigned short*)alloc((size_t)4 * 1025 * 12288 * 2);
  unsigned short* zpred_ = zbuf;  // alias: lifetimes disjoint
  float* attnP = (float*)zbuf;    // alias: partials live between qkv and Wo GEMMs
  float* x           = (float*)alloc((size_t)4096 * 768 * 4);
  unsigned short* xb = (unsigned short*)alloc((size_t)4096 * 768 * 2);
  float* qb  = (float*)alloc((size_t)4096 * 192 * 4);
  float* kb  = (float*)alloc((size_t)4096 * 192 * 4);
  float* vb  = (float*)alloc((size_t)4096 * 192 * 4);
  unsigned short* ob = (unsigned short*)alloc((size_t)4096 * 192 * 2);
  float* Dz  = (float*)alloc((size_t)4096 * 768 * 4);
  int* idxo  = (int*)alloc((size_t)4096 * 32 * 4);
  float* valo = (float*)alloc((size_t)4096 * 32 * 4);
  const size_t WQKV = (size_t)192 * 12288;   // per (layer, weight)
  unsigned short* WqkvT = (unsigned short*)alloc((size_t)6 * WQKV * 2);
  unsigned short* WoT   = (unsigned short*)alloc((size_t)2 * 12288 * 192 * 2);
  unsigned short* Dbt   = (unsigned short*)alloc((size_t)12288 * 768 * 2);
  unsigned short* Dt    = (unsigned short*)alloc((size_t)768 * 12288 * 2);
  const size_t NEED = off;  // ~219.8 MB (confirmed fitting in R5/R6)
  // qkv split-1 partials alias the (dead at qkv time) Dz buffer: 9.44 MB <= 12.6 MB
  float* P2 = Dz;

  if (ws_size < NEED) {  // safety net (should never fire)
    fill_out_zero<<<(out_size + 255) / 256, 256, 0, stream>>>((float*)d_out, out_size);
    return;
  }

  init_x<<<12288, 256, 0, stream>>>(xin, bvec, x, xb);
  conv_f2b<<<9216, 256, 0, stream>>>(D, Dbt);
  transpose_f2b<<<dim3(384, 24), 256, 0, stream>>>(D, Dt, 12288, 768);
  for (int l = 0; l < 2; ++l) {
    transpose_f2b<<<dim3(384, 6), 256, 0, stream>>>(
        Wq + (size_t)l * 12288 * 192, WqkvT + (size_t)(l * 3 + 0) * WQKV, 12288, 192);
    transpose_f2b<<<dim3(384, 6), 256, 0, stream>>>(
        Wk + (size_t)l * 12288 * 192, WqkvT + (size_t)(l * 3 + 1) * WQKV, 12288, 192);
    transpose_f2b<<<dim3(384, 6), 256, 0, stream>>>(
        Wv + (size_t)l * 12288 * 192, WqkvT + (size_t)(l * 3 + 2) * WQKV, 12288, 192);
    transpose_f2b<<<dim3(6, 384), 256, 0, stream>>>(
        Wo + (size_t)l * 192 * 12288, WoT + (size_t)l * 12288 * 192, 192, 12288);
  }

  for (int l = 0; l < 2; ++l) {
    // z_in = relu(LAM * x @ D^T) -> zbuf shifted rows [b*1025+1 ..]
    // 256^2 tile: grid 16x48 -> 1-D 768, XCD-rect 16x x 6y (B 2.4 MB/XCD)
    gemm_bt2<unsigned short, true, 1, false, false, 16, 48, 1, 16, 6>
        <<<768, 512, 0, stream>>>(xb, Dbt, zbuf, nullptr, 768, 12288, LAM);
    // k/v row-0 prefill (= zero-context bias row); qb fully written by qkv s=0.
    fill_bias<<<3072, 256, 0, stream>>>(kb, bk + (size_t)l * 192, 192);
    fill_bias<<<3072, 256, 0, stream>>>(vb, bv + (size_t)l * 192, 192);
    // P2 zero-prefill (rows (b,0) of k/v planes must read as 0 in the merge)
    fill_bias<<<9216, 256, 0, stream>>>(P2, nullptr, 192);
    // atomic-free fused q/k/v: split 0 -> final bufs, split 1 -> P2; merge.
    gemm_qkv<<<384, 256, 0, stream>>>(
        zbuf, WqkvT + (size_t)(l * 3) * WQKV,
        bq + (size_t)l * 192, bk + (size_t)l * 192, bv + (size_t)l * 192,
        qb, kb, vb, P2);
    qkv_merge<<<2304, 256, 0, stream>>>(P2, qb, kb, vb);
    // Attention (z_in in zbuf is dead now; attnP scratch aliases it)
    attn_pass1<<<2304, 256, 0, stream>>>(qb, kb, vb, attnP);
    attn_merge<<<4096, 192, 0, stream>>>(attnP, ob);
    // z_pred_ = relu(o @ Wo + bo) -> zpred_ (aliases zbuf; attnP dead)
    gemm_bt2<unsigned short, true, 0, true, false, 16, 48, 1, 16, 6>
        <<<768, 512, 0, stream>>>(
        ob, WoT + (size_t)l * 12288 * 192, zpred_, bo + (size_t)l * 12288, 192, 12288, 1.0f);
    // Dz = z_pred_ @ D  (256^2, split-K=4 -> 192 blocks)
    fill_bias<<<12288, 256, 0, stream>>>(Dz, nullptr, 768);
    gemm_bt2<float, false, 0, false, true, 16, 3, 4, 8, 3>
        <<<192, 512, 0, stream>>>(zpred_, Dt, Dz, nullptr, 12288, 768, 1.0f);
    proj_update<<<4096, 256, 0, stream>>>(Dz, x, xb);
  }
  // z_novel = relu(LAM * x @ D^T) -> zbuf shifted rows
  gemm_bt2<unsigned short, true, 1, false, false, 16, 48, 1, 16, 6>
      <<<768, 512, 0, stream>>>(xb, Dbt, zbuf, nullptr, 768, 12288, LAM);
  topk_rows<<<4096, 256, 0, stream>>>(zbuf, idxo, valo);
  sparse_recons<<<4096, 256, 0, stream>>>(idxo, valo, x, xin, D, (float*)d_out);
}

// Round 14
// 1265.983 us; speedup vs baseline: 1.0958x; 1.0297x over previous
//
#include <hip/hip_runtime.h>
#include <hip/hip_bf16.h>

typedef __attribute__((ext_vector_type(4))) float f32x4;
typedef __attribute__((ext_vector_type(8))) short short8;
typedef __attribute__((ext_vector_type(8))) unsigned short ushort8;
typedef __attribute__((ext_vector_type(4))) unsigned short ushort4v;
typedef __attribute__((ext_vector_type(4))) unsigned int uint4v;

#define DEVFN __device__ __forceinline__

DEVFN float b2f(unsigned short u) { return __uint_as_float(((unsigned)u) << 16); }
DEVFN unsigned short f2b(float f) {
  __hip_bfloat16 h = __float2bfloat16(f);
  return __builtin_bit_cast(unsigned short, h);
}

DEVFN void load_lds16(const void* g, void* l) {
  __builtin_amdgcn_global_load_lds(
      (const __attribute__((address_space(1))) unsigned int*)g,
      (__attribute__((address_space(3))) unsigned int*)l, 16, 0, 0);
}

// ===========================================================================

__global__ void fill_out_zero(float* o, int n) {
  int i = blockIdx.x * 256 + threadIdx.x;
  if (i < n) o[i] = 0.0f;
}

__global__ __launch_bounds__(256) void init_x(
    const float* __restrict__ xin, const float* __restrict__ bvec,
    float* __restrict__ x, unsigned short* __restrict__ xb) {
  size_t i = (size_t)blockIdx.x * 256 + threadIdx.x;
  int col = (int)(i % 768);
  float v = xin[i] - bvec[col];
  x[i] = v;
  xb[i] = f2b(v);
}

// buf[i] = bias[i % ld] (or 0 if bias null)
__global__ __launch_bounds__(256) void fill_bias(
    float* __restrict__ buf, const float* __restrict__ bias, int ld) {
  size_t i = (size_t)blockIdx.x * 256 + threadIdx.x;
  buf[i] = bias ? bias[(int)(i % ld)] : 0.0f;
}

// f32 -> bf16 straight convert, 4 elems/thread (n must be /1024)
__global__ __launch_bounds__(256) void conv_f2b(
    const float* __restrict__ in, unsigned short* __restrict__ out) {
  size_t i = ((size_t)blockIdx.x * 256 + threadIdx.x) * 4;
  f32x4 v = *(const f32x4*)(in + i);
  ushort4v w;
#pragma unroll
  for (int e = 0; e < 4; ++e) w[e] = f2b(v[e]);
  *(ushort4v*)(out + i) = w;
}

// out[c][r] = bf16(in[r][c]); R,C multiples of 32; grid (R/32, C/32)
__global__ __launch_bounds__(256) void transpose_f2b(
    const float* __restrict__ in, unsigned short* __restrict__ out,
    int R, int C) {
  __shared__ float tile[32][33];
  int r0 = blockIdx.x * 32, c0 = blockIdx.y * 32;
  int tx = threadIdx.x & 31, ty = threadIdx.x >> 5;
#pragma unroll
  for (int i = 0; i < 4; ++i)
    tile[ty + i * 8][tx] = in[(size_t)(r0 + ty + i * 8) * C + c0 + tx];
  __syncthreads();
#pragma unroll
  for (int i = 0; i < 4; ++i)
    out[(size_t)(c0 + ty + i * 8) * R + r0 + tx] = f2b(tile[tx][ty + i * 8]);
}

// ---------------------------------------------------------------------------
// XCD-rectangle decode: 1-D launch of GX * GY * GZ blocks. bid&7 picks an
// XCD-rectangle (assumes round-robin bid%8 -> XCD; if wrong, perf-neutral).
// Rectangle = RX row-blocks x RG group-ids (g = y + GY*z), g varies fastest.
// Row order is STAGGERED per g-rect so split-K atomic targets of the same
// output tile are never RMW'd from multiple XCDs in lockstep.
// ---------------------------------------------------------------------------
template <int GX, int GY, int GZ, int RX, int RG>
DEVFN void rect_decode(int bid, int& x, int& y, int& z) {
  constexpr int NRG = (GY * GZ) / RG;   // rectangles along g
  const int xcd = bid & 7;
  const int rr = bid >> 3;              // [0, RX*RG)
  const int rgx = xcd % NRG, rxx = xcd / NRG;
  const int gl = rr % RG;
  int xl = rr / RG;
  xl = (xl + rgx * (RX / NRG)) % RX;    // stagger rows across g-rects
  const int g = rgx * RG + gl;
  x = rxx * RX + xl;
  y = g % GY;
  z = g / GY;
}

// ---------------------------------------------------------------------------
// gemm_bt2: C[M,N] = epi(alpha * A[M,K] . B[N,K]^T + bias)  both bf16 K-major.
// 256x256 tile, BK=64, 512 threads (8 waves, 2M x 4N, 128x64 out each).
// Double-buffered global_load_lds staging + XOR-swizzle (conflict-free).
// T4 counted-vmcnt pipeline: each thread issues exactly 8 loads per stage;
// after issuing stage(t+1), s_waitcnt vmcnt(8) waits only for stage(t)'s
// loads; RAW s_barrier (no vmcnt(0) drain) -> stage(t+1) stays in flight
// across the barrier and lands under compute(t). Two raw barriers/iter.
// NOTE: NO setprio here — R13 measured it at −9% on this lockstep
// structure (replicates m190: setprio needs phase role-split to pay).
// SC=1: C rows shifted per batch. 1-D grid, XCD-rectangle scheduled.
// ---------------------------------------------------------------------------
template <typename CT, bool RELU, int SC, bool BIAS, bool SPLITK,
          int GX, int GY, int GZ, int RX, int RG>
__global__ __launch_bounds__(512, 2) void gemm_bt2(
    const unsigned short* __restrict__ A, const unsigned short* __restrict__ B,
    CT* __restrict__ C, const float* __restrict__ bias,
    int K, int ldc, float alpha) {
  __shared__ unsigned short sA[2][256 * 64];   // 64 KB
  __shared__ unsigned short sB[2][256 * 64];   // 64 KB
  const int tid = threadIdx.x;
  const int wave = tid >> 6, lane = tid & 63;
  int bx, by, bz;
  rect_decode<GX, GY, GZ, RX, RG>((int)blockIdx.x, bx, by, bz);
  const int row0 = bx * 256, col0 = by * 256;
  const unsigned short* Ab = A + (size_t)row0 * K;
  const unsigned short* Bb = B + (size_t)col0 * K;
  const int srow = lane >> 3;
  const int swc = ((lane & 7) ^ srow) * 8;       // pre-swizzled global col
  const int wm = wave & 1, wn = wave >> 1;       // 2 x 4 wave grid
  const int lr = lane & 15;
  const int hi = lane >> 4;
  const int l7 = lane & 7;
  const int ksw0 = (hi ^ l7) * 8;                // swizzled LDS slot, ks=0
  const int ksw1 = ((4 + hi) ^ l7) * 8;          // swizzled LDS slot, ks=1
  const int klen = SPLITK ? (K / GZ) : K;
  const int kbeg = SPLITK ? bz * klen : 0;
  const int nt = klen / 64;
  f32x4 acc[8][4] = {};
  auto stage = [&](int buf, int t) {
    const int k0 = kbeg + t * 64;
    // 64 chunks of 8 rows x 64 cols: 0..31 = A, 32..63 = B; 8 loads/thread
#pragma unroll
    for (int it = 0; it < 8; ++it) {
      int c = wave * 8 + it;
      if (c < 32) {
        int r = c * 8 + srow;
        load_lds16(Ab + (size_t)r * K + k0 + swc, &sA[buf][c * 512]);
      } else {
        int cb = c - 32;
        int r = cb * 8 + srow;
        load_lds16(Bb + (size_t)r * K + k0 + swc, &sB[buf][cb * 512]);
      }
    }
  };
  stage(0, 0);
  for (int t = 0; t < nt; ++t) {
    const int cur = t & 1;
    if (t + 1 < nt) {
      stage(cur ^ 1, t + 1);                       // 8 newer loads in flight
      asm volatile("s_waitcnt vmcnt(8)" ::: "memory");  // stage(t) landed
    } else {
      asm volatile("s_waitcnt vmcnt(0)" ::: "memory");
    }
    __builtin_amdgcn_s_barrier();                  // raw: no vmem drain
    asm volatile("" ::: "memory");
    const unsigned short* cA = &sA[cur][0];
    const unsigned short* cB = &sB[cur][0];
#pragma unroll
    for (int ks = 0; ks < 2; ++ks) {
      const int ko = ks ? ksw1 : ksw0;
      short8 af[8], bfr[4];
#pragma unroll
      for (int i = 0; i < 8; ++i)
        af[i] = *(const short8*)&cA[(wm * 128 + i * 16 + lr) * 64 + ko];
#pragma unroll
      for (int j = 0; j < 4; ++j)
        bfr[j] = *(const short8*)&cB[(wn * 64 + j * 16 + lr) * 64 + ko];
#pragma unroll
      for (int i = 0; i < 8; ++i)
#pragma unroll
        for (int j = 0; j < 4; ++j)
          acc[i][j] = __builtin_amdgcn_mfma_f32_16x16x32_bf16(af[i], bfr[j], acc[i][j], 0, 0, 0);
    }
    asm volatile("" ::: "memory");
    __builtin_amdgcn_s_barrier();                  // buf reuse safe
  }
  const int rc = (SC == 0) ? 0 : ((row0 >> 10) + 1);
  const int rbase = row0 + rc + wm * 128 + (lane >> 4) * 4;
  const int cbase = col0 + wn * 64 + lr;
#pragma unroll
  for (int j = 0; j < 4; ++j) {
    int col = cbase + j * 16;
    float bv = BIAS ? bias[col] : 0.0f;
#pragma unroll
    for (int i = 0; i < 8; ++i) {
#pragma unroll
      for (int r = 0; r < 4; ++r) {
        float vv = acc[i][j][r] * alpha;
        size_t off = (size_t)(rbase + i * 16 + r) * ldc + col;
        if constexpr (SPLITK) {
          atomicAdd((float*)C + off, vv);
        } else {
          vv += bv;
          if (RELU) vv = fmaxf(vv, 0.0f);
          if constexpr (sizeof(CT) == 2) ((unsigned short*)C)[off] = f2b(vv);
          else C[off] = vv;
        }
      }
    }
  }
}

// ---------------------------------------------------------------------------
// gemm_qkv: fused q/k/v projection, ATOMIC-FREE. 384 blocks.
// BM=64, BN=192, split-K=2 (k-halves of 6144). combo = (weight, s):
//   s=0 -> streams bias+partial into qb/kb/vb (shifted rows for k/v;
//          in-batch row 0 keeps the bias prefill, in-batch row 1023 dropped)
//   s=1 -> streams partial into P2[w] (same shift; P2 zero-prefilled)
// then qkv_merge adds P2 into the final buffers. Zero atomics.
// A-LOCALITY remap: combo varies FASTEST within an XCD (combo = rr%6,
// row = xcd*8 + rr/6, bijective over 384) -> the 6 co-resident combos of a
// row-batch read the SAME 1.5 MB A-panel (L2-hit x6).
// Counted-vmcnt double-buffer pipeline (8 loads/thread per stage).
// ---------------------------------------------------------------------------
__global__ __launch_bounds__(256) void gemm_qkv(
    const unsigned short* __restrict__ A, const unsigned short* __restrict__ Bq,
    const float* __restrict__ bq, const float* __restrict__ bk,
    const float* __restrict__ bv,
    float* __restrict__ qb, float* __restrict__ kb, float* __restrict__ vb,
    float* __restrict__ P2) {
  __shared__ unsigned short sA[2][64 * 64];    // 16 KB
  __shared__ unsigned short sB[2][192 * 64];   // 48 KB
  const int tid = threadIdx.x;
  const int wave = tid >> 6, lane = tid & 63;
  const int bid = (int)blockIdx.x;
  const int xcd = bid & 7;
  const int rr = bid >> 3;                  // [0,48)
  const int combo = rr % 6;                 // combo fastest (A L2 reuse x6)
  const int row = xcd * 8 + rr / 6;         // row-block [0,64)
  const int wz = combo >> 1;                // weight: 0=q,1=k,2=v
  const int s = combo & 1;                  // k-half
  const int shift = (wz > 0);
  const unsigned short* B = Bq + (size_t)wz * 192 * 12288;
  const float* bias = (wz == 0) ? bq : (wz == 1 ? bk : bv);
  float* dst = (s == 0) ? ((wz == 0) ? qb : (wz == 1 ? kb : vb))
                        : (P2 + (size_t)wz * 786432);
  const int row0 = row * 64;
  const int ra = (row0 >> 10) + 1;          // z_in view
  const unsigned short* Ab = A + (size_t)(row0 + ra) * 12288;
  const int srow = lane >> 3;
  const int swc = ((lane & 7) ^ srow) * 8;  // pre-swizzled global col
  const int wm = wave & 1, wn = wave >> 1;
  const int lr = lane & 15;
  const int hi = lane >> 4;
  const int l7 = lane & 7;
  const int ksw0 = (hi ^ l7) * 8;
  const int ksw1 = ((4 + hi) ^ l7) * 8;
  const int kbeg = s * 6144;
  f32x4 acc[2][6] = {};
  auto stage = [&](int buf, int t) {
    const int k0 = kbeg + t * 64;
    // 32 chunks of 8 rows: 0..7 = A (64 rows), 8..31 = B; 8 loads/thread
#pragma unroll
    for (int it = 0; it < 8; ++it) {
      int c = wave * 8 + it;
      if (c < 8) {
        int r = c * 8 + srow;
        load_lds16(Ab + (size_t)r * 12288 + k0 + swc, &sA[buf][c * 512]);
      } else {
        int cb = c - 8;
        int r = cb * 8 + srow;
        load_lds16(B + (size_t)r * 12288 + k0 + swc, &sB[buf][cb * 512]);
      }
    }
  };
  stage(0, 0);
  for (int t = 0; t < 96; ++t) {
    const int cur = t & 1;
    if (t + 1 < 96) {
      stage(cur ^ 1, t + 1);
      asm volatile("s_waitcnt vmcnt(8)" ::: "memory");
    } else {
      asm volatile("s_waitcnt vmcnt(0)" ::: "memory");
    }
    __builtin_amdgcn_s_barrier();
    asm volatile("" ::: "memory");
    const unsigned short* cA = &sA[cur][0];
    const unsigned short* cB = &sB[cur][0];
#pragma unroll
    for (int ks = 0; ks < 2; ++ks) {
      const int ko = ks ? ksw1 : ksw0;
      short8 af[2], bfr[6];
#pragma unroll
      for (int i = 0; i < 2; ++i)
        af[i] = *(const short8*)&cA[(wm * 32 + i * 16 + lr) * 64 + ko];
#pragma unroll
      for (int j = 0; j < 6; ++j)
        bfr[j] = *(const short8*)&cB[(wn * 96 + j * 16 + lr) * 64 + ko];
#pragma unroll
      for (int i = 0; i < 2; ++i)
#pragma unroll
        for (int j = 0; j < 6; ++j)
          acc[i][j] = __builtin_amdgcn_mfma_f32_16x16x32_bf16(af[i], bfr[j], acc[i][j], 0, 0, 0);
    }
    asm volatile("" ::: "memory");
    __builtin_amdgcn_s_barrier();
  }
  const int rbase = row0 + wm * 32 + (lane >> 4) * 4;
  const int cbase = wn * 96 + lr;
#pragma unroll
  for (int j = 0; j < 6; ++j) {
    int col = cbase + j * 16;
    float bvv = (s == 0) ? bias[col] : 0.0f;
#pragma unroll
    for (int i = 0; i < 2; ++i)
#pragma unroll
      for (int r = 0; r < 4; ++r) {
        int rw = rbase + i * 16 + r;
        if (shift) {
          if ((rw & 1023) == 1023) continue;  // dropped (next batch row 0 = bias)
          rw += 1;
        }
        dst[(size_t)rw * 192 + col] = acc[i][j][r] + bvv;
      }
  }
}

// dst[w] += P2[w] elementwise over 3 x 4096 x 192 floats
__global__ __launch_bounds__(256) void qkv_merge(
    const float* __restrict__ P2, float* __restrict__ qb,
    float* __restrict__ kb, float* __restrict__ vb) {
  size_t i = ((size_t)blockIdx.x * 256 + threadIdx.x) * 4;
  const int plane = (int)(i / 786432);
  const size_t o = i - (size_t)plane * 786432;
  float* dst = plane == 0 ? qb : (plane == 1 ? kb : vb);
  f32x4 a = *(const f32x4*)(P2 + i);
  f32x4 b = *(const f32x4*)(dst + o);
#pragma unroll
  for (int e = 0; e < 4; ++e) b[e] += a[e];
  *(f32x4*)(dst + o) = b;
}

// ---------------------------------------------------------------------------
// Attention pass 1, BLOCK-COOPERATIVE: block = (b, h, q-quad j, chunk c).
// 4 waves handle qgroups 4j..4j+3 against ONE 128-row K/V chunk staged in
// LDS (24 KB). All qgroups of quad j have g8 = j>>1, so quad j needs chunks
// 0..(j>>1): 72 block-tasks per (b,h) via off(j) = a^2+a+(j&1)(a+1), a=j>>1.
// Grid 2304, XCD-local on bh (xcd owns bh in [4*xcd, 4*xcd+4)).
// Partials P[task][wave*16+qi] = {m, l, ov[24]} stride 28 floats.
// ---------------------------------------------------------------------------
__global__ __launch_bounds__(256) void attn_pass1(
    const float* __restrict__ q, const float* __restrict__ k,
    const float* __restrict__ v, float* __restrict__ P) {
  __shared__ float sK[128 * 24];   // 12 KB
  __shared__ float sV[128 * 24];   // 12 KB
  const int tid = threadIdx.x;
  const int wave = tid >> 6, lane = tid & 63;
  const int xcd = (int)blockIdx.x & 7;
  const int r0 = (int)blockIdx.x >> 3;        // [0,288)
  const int bh = xcd * 4 + r0 / 72;
  const int t = r0 % 72;                      // [0,72)
  const int b = bh >> 3, h = bh & 7;
  // decode t -> (quad jq, chunk c)
  int jq = 0;
  while (true) {
    int jn = jq + 1;
    int a2 = jn >> 1;
    int offn = a2 * a2 + a2 + (jn & 1) * (a2 + 1);
    if (jn < 16 && offn <= t) jq = jn; else break;
  }
  const int aq = jq >> 1;
  const int offj = aq * aq + aq + (jq & 1) * (aq + 1);
  const int c = t - offj;                     // chunk in [0, jq>>1]
  const int qg = jq * 4 + wave;               // this wave's qgroup
  const int qi = lane & 15, ks = lane >> 4;
  const int qpos = qg * 16 + qi;
  const int n = b * 1024 + qpos;
  const int task = bh * 72 + t;
  // stage chunk K/V (128 rows x 24 floats) into LDS; fully coalesced f32x4
  {
    const float* kg = k + (size_t)(b * 1024 + c * 128) * 192 + h * 24;
    const float* vg = v + (size_t)(b * 1024 + c * 128) * 192 + h * 24;
#pragma unroll
    for (int i = 0; i < 3; ++i) {
      int idx = tid + i * 256;               // [0,768)
      int row = idx / 6, seg = idx - row * 6;
      *(f32x4*)&sK[row * 24 + seg * 4] =
          *(const f32x4*)(kg + (size_t)row * 192 + seg * 4);
      *(f32x4*)&sV[row * 24 + seg * 4] =
          *(const f32x4*)(vg + (size_t)row * 192 + seg * 4);
    }
  }
  const float scale = 0.20412414523193154f;  // 1/sqrt(24)
  float qv[24];
  const float* qr = q + (size_t)n * 192 + h * 24;
#pragma unroll
  for (int d = 0; d < 24; ++d) qv[d] = qr[d] * scale;
  __syncthreads();
  float m = -1e30f, l = 0.0f, ov[24] = {};
  const int kb0 = c * 128;
  const int kend = min(qpos, kb0 + 127);
  for (int kp = kb0 + ks; kp <= kend; kp += 4) {
    const f32x4* kr = (const f32x4*)&sK[(kp - kb0) * 24];
    float s0 = 0.0f, s1 = 0.0f, s2 = 0.0f;
#pragma unroll
    for (int j = 0; j < 2; ++j) {
      f32x4 k0 = kr[j * 3 + 0], k1 = kr[j * 3 + 1], k2 = kr[j * 3 + 2];
#pragma unroll
      for (int e = 0; e < 4; ++e) {
        s0 += qv[(j * 3 + 0) * 4 + e] * k0[e];
        s1 += qv[(j * 3 + 1) * 4 + e] * k1[e];
        s2 += qv[(j * 3 + 2) * 4 + e] * k2[e];
      }
    }
    float s = s0 + s1 + s2;
    float mn = fmaxf(m, s);
    float corr = __expf(m - mn);
    float p = __expf(s - mn);
    const f32x4* vr = (const f32x4*)&sV[(kp - kb0) * 24];
    l = l * corr + p;
#pragma unroll
    for (int j = 0; j < 6; ++j) {
      f32x4 vvv = vr[j];
#pragma unroll
      for (int e = 0; e < 4; ++e) ov[j * 4 + e] = ov[j * 4 + e] * corr + p * vvv[e];
    }
    m = mn;
  }
  // merge the 4 k-slices (lanes qi, qi+16, qi+32, qi+48)
#pragma unroll
  for (int off = 16; off < 64; off <<= 1) {
    float m2 = __shfl_xor(m, off);
    float l2 = __shfl_xor(l, off);
    float mn = fmaxf(m, m2);
    float c1 = __expf(m - mn), c2 = __expf(m2 - mn);
    l = l * c1 + l2 * c2;
#pragma unroll
    for (int d = 0; d < 24; ++d) {
      float o2 = __shfl_xor(ov[d], off);
      ov[d] = ov[d] * c1 + o2 * c2;
    }
    m = mn;
  }
  if (ks == 0) {
    float* pr = P + ((size_t)task * 64 + wave * 16 + qi) * 28;
    pr[0] = m;
    pr[1] = l;
#pragma unroll
    for (int d = 0; d < 24; ++d) pr[2 + d] = ov[d];
  }
}

__global__ __launch_bounds__(192) void attn_merge(
    const float* __restrict__ P, unsigned short* __restrict__ o) {
  const int n = blockIdx.x;            // 0..4095
  const int tid = threadIdx.x;
  const int h = tid / 24, d = tid - h * 24;
  const int b = n >> 10, qpos = n & 1023;
  const int qg = qpos >> 4, qi = qpos & 15;
  const int j = qg >> 2, w = qg & 3;
  const int a = j >> 1;                // == g8
  const int nch = a + 1;
  const int offj = a * a + a + (j & 1) * (a + 1);
  const int bh = b * 8 + h;
  const int base = bh * 72 + offj;
  float M = -1e30f;
  for (int cc = 0; cc < nch; ++cc)
    M = fmaxf(M, P[((size_t)(base + cc) * 64 + w * 16 + qi) * 28]);
  float L = 0.0f, OV = 0.0f;
  for (int cc = 0; cc < nch; ++cc) {
    const float* pr = P + ((size_t)(base + cc) * 64 + w * 16 + qi) * 28;
    float wgt = __expf(pr[0] - M);
    L += pr[1] * wgt;
    OV += pr[2 + d] * wgt;
  }
  o[(size_t)n * 192 + h * 24 + d] = f2b(OV / L);
}

// per-row: p = dot(Dz,x)/(||Dz||+eps)^2 ; x -= p*Dz ; xb = bf16(x)
__global__ __launch_bounds__(256) void proj_update(
    const float* __restrict__ Dz, float* __restrict__ x,
    unsigned short* __restrict__ xb) {
  const int n = blockIdx.x;
  const int tid = threadIdx.x;
  const float* dz = Dz + (size_t)n * 768;
  float* xr = x + (size_t)n * 768;
  float dot = 0.0f, s2 = 0.0f;
  for (int i = tid; i < 768; i += 256) {
    float a = dz[i], c = xr[i];
    dot += a * c;
    s2 += a * a;
  }
#pragma unroll
  for (int o2 = 32; o2; o2 >>= 1) {
    dot += __shfl_down(dot, o2);
    s2 += __shfl_down(s2, o2);
  }
  __shared__ float sd[4], ss[4], sp;
  const int wave = tid >> 6, lane = tid & 63;
  if (lane == 0) { sd[wave] = dot; ss[wave] = s2; }
  __syncthreads();
  if (tid == 0) {
    float Dd = sd[0] + sd[1] + sd[2] + sd[3];
    float S = ss[0] + ss[1] + ss[2] + ss[3];
    float nrm = sqrtf(S) + 1e-6f;
    sp = Dd / (nrm * nrm);
  }
  __syncthreads();
  float p = sp;
  for (int i = tid; i < 768; i += 256) {
    float nx = xr[i] - p * dz[i];
    xr[i] = nx;
    xb[(size_t)n * 768 + i] = f2b(nx);
  }
}

DEVFN int sanitize(int v) { return (v & 0x8000) ? 0 : v; }  // -0/neg codes -> 0

// top-32 of z_novel row (bf16 codes nonneg => int order = value order);
// emits 32 (idx,val) pairs per row (slot order arbitrary).
__global__ __launch_bounds__(256) void topk_rows(
    const unsigned short* __restrict__ zbuf, int* __restrict__ idxo,
    float* __restrict__ valo) {
  const int n = blockIdx.x;
  const int b = n >> 10;
  const int tid = threadIdx.x;
  const int wave = tid >> 6, lane = tid & 63;
  const uint4v* zr = (const uint4v*)(zbuf + (size_t)(n + b + 1) * 12288);
  uint4v pk[6];
#pragma unroll
  for (int j = 0; j < 6; ++j) pk[j] = zr[tid * 6 + j];
  __shared__ int swsum[4];
  __shared__ int seq[256];
  __shared__ int spcnt;
  int lo = 0, hi = 0x7F7F;
  while (lo < hi) {
    int mid = (lo + hi) >> 1;
    int c = 0;
#pragma unroll
    for (int j = 0; j < 6; ++j)
#pragma unroll
      for (int e = 0; e < 4; ++e) {
        unsigned int u = pk[j][e];
        c += (sanitize((int)(u & 0xffffu)) > mid) + (sanitize((int)(u >> 16)) > mid);
      }
#pragma unroll
    for (int o2 = 32; o2; o2 >>= 1) c += __shfl_down(c, o2);
    if (lane == 0) swsum[wave] = c;
    __syncthreads();
    int total = swsum[0] + swsum[1] + swsum[2] + swsum[3];
    __syncthreads();
    if (total < 32) hi = mid; else lo = mid + 1;
  }
  const int T = lo;
  int cgt = 0, ceq = 0;
#pragma unroll
  for (int j = 0; j < 6; ++j)
#pragma unroll
    for (int e = 0; e < 4; ++e) {
      unsigned int u = pk[j][e];
      int v0 = sanitize((int)(u & 0xffffu)), v1 = sanitize((int)(u >> 16));
      cgt += (v0 > T) + (v1 > T);
      ceq += (v0 == T) + (v1 == T);
    }
  int cg = cgt;
#pragma unroll
  for (int o2 = 32; o2; o2 >>= 1) cg += __shfl_down(cg, o2);
  if (lane == 0) swsum[wave] = cg;
  seq[tid] = ceq;
  if (tid == 0) spcnt = 0;
  __syncthreads();
  const int total_gt = swsum[0] + swsum[1] + swsum[2] + swsum[3];
  for (int o2 = 1; o2 < 256; o2 <<= 1) {
    int vv = (tid >= o2) ? seq[tid - o2] : 0;
    __syncthreads();
    seq[tid] += vv;
    __syncthreads();
  }
  const int quota = 32 - total_gt;
  int rank = seq[tid] - ceq;
  int* irow = idxo + (size_t)n * 32;
  float* vrow = valo + (size_t)n * 32;
#pragma unroll
  for (int j = 0; j < 6; ++j)
#pragma unroll
    for (int e = 0; e < 4; ++e) {
      unsigned int u = pk[j][e];
#pragma unroll
      for (int hf = 0; hf < 2; ++hf) {
        int v = sanitize(hf ? (int)(u >> 16) : (int)(u & 0xffffu));
        bool kp = false;
        if (v > T) kp = true;
        else if (v == T) { if (rank < quota) kp = true; ++rank; }
        if (kp) {
          int pos = atomicAdd(&spcnt, 1);
          irow[pos] = tid * 48 + j * 8 + e * 2 + hf;
          vrow[pos] = b2f((unsigned short)v);
        }
      }
    }
}

// out = x_input - x_final + sum_j val_j * D[idx_j,:]   (f32 in, f32 out)
__global__ __launch_bounds__(256) void sparse_recons(
    const int* __restrict__ idxo, const float* __restrict__ valo,
    const float* __restrict__ x, const float* __restrict__ xin,
    const float* __restrict__ D, float* __restrict__ out) {
  const int n = blockIdx.x;
  const int t = threadIdx.x;
  __shared__ int sidx[32];
  __shared__ float sval[32];
  if (t < 32) { sidx[t] = idxo[(size_t)n * 32 + t]; sval[t] = valo[(size_t)n * 32 + t]; }
  __syncthreads();
  float acc[3];
#pragma unroll
  for (int u = 0; u < 3; ++u) {
    size_t i = (size_t)n * 768 + t + u * 256;
    acc[u] = xin[i] - x[i];
  }
  for (int j = 0; j < 32; ++j) {
    size_t base = (size_t)sidx[j] * 768;
    float vj = sval[j];
#pragma unroll
    for (int u = 0; u < 3; ++u) acc[u] += vj * D[base + t + u * 256];
  }
#pragma unroll
  for (int u = 0; u < 3; ++u) out[(size_t)n * 768 + t + u * 256] = acc[u];
}

// ===========================================================================
extern "C" void kernel_launch(void* const* d_in, const int* in_sizes, int n_in,
                              void* d_out, int out_size, void* d_ws, size_t ws_size,
                              hipStream_t stream) {
  (void)in_sizes; (void)n_in;
  const float* xin  = (const float*)d_in[0];
  const float* D    = (const float*)d_in[1];
  const float* bvec = (const float*)d_in[2];
  const float* Wq   = (const float*)d_in[3];
  const float* bq   = (const float*)d_in[4];
  const float* Wk   = (const float*)d_in[5];
  const float* bk   = (const float*)d_in[6];
  const float* Wv   = (const float*)d_in[7];
  const float* bv   = (const float*)d_in[8];
  const float* Wo   = (const float*)d_in[9];
  const float* bo   = (const float*)d_in[10];
  const float LAM = 1.0f / 3072.0f;

  char* ws = (char*)d_ws;
  size_t off = 0;
  auto alloc = [&](size_t bytes) {
    void* p = ws + off;
    off += (bytes + 255) & ~(size_t)255;
    return p;
  };
  unsigned short* zbuf = (unsigned short*)alloc((size_t)4 * 1025 * 12288 * 2);
  unsigned short* zpred_ = zbuf;  // alias: lifetimes disjoint
  float* attnP = (float*)zbuf;    // alias: partials live between qkv and Wo GEMMs
  float* x           = (float*)alloc((size_t)4096 * 768 * 4);
  unsigned short* xb = (unsigned short*)alloc((size_t)4096 * 768 * 2);
  float* qb  = (float*)alloc((size_t)4096 * 192 * 4);
  float* kb  = (float*)alloc((size_t)4096 * 192 * 4);
  float* vb  = (float*)alloc((size_t)4096 * 192 * 4);
  unsigned short* ob = (unsigned short*)alloc((size_t)4096 * 192 * 2);
  float* Dz  = (float*)alloc((size_t)4096 * 768 * 4);
  int* idxo  = (int*)alloc((size_t)4096 * 32 * 4);
  float* valo = (float*)alloc((size_t)4096 * 32 * 4);
  const size_t WQKV = (size_t)192 * 12288;   // per (layer, weight)
  unsigned short* WqkvT = (unsigned short*)alloc((size_t)6 * WQKV * 2);
  unsigned short* WoT   = (unsigned short*)alloc((size_t)2 * 12288 * 192 * 2);
  unsigned short* Dbt   = (unsigned short*)alloc((size_t)12288 * 768 * 2);
  unsigned short* Dt    = (unsigned short*)alloc((size_t)768 * 12288 * 2);
  const size_t NEED = off;  // ~219.8 MB (confirmed fitting in R5/R6)
  // qkv split-1 partials alias the (dead at qkv time) Dz buffer: 9.44 MB <= 12.6 MB
  float* P2 = Dz;

  if (ws_size < NEED) {  // safety net (should never fire)
    fill_out_zero<<<(out_size + 255) / 256, 256, 0, stream>>>((float*)d_out, out_size);
    return;
  }

  init_x<<<12288, 256, 0, stream>>>(xin, bvec, x, xb);
  conv_f2b<<<9216, 256, 0, stream>>>(D, Dbt);
  transpose_f2b<<<dim3(384, 24), 256, 0, stream>>>(D, Dt, 12288, 768);
  for (int l = 0; l < 2; ++l) {
    transpose_f2b<<<dim3(384, 6), 256, 0, stream>>>(
        Wq + (size_t)l * 12288 * 192, WqkvT + (size_t)(l * 3 + 0) * WQKV, 12288, 192);
    transpose_f2b<<<dim3(384, 6), 256, 0, stream>>>(
        Wk + (size_t)l * 12288 * 192, WqkvT + (size_t)(l * 3 + 1) * WQKV, 12288, 192);
    transpose_f2b<<<dim3(384, 6), 256, 0, stream>>>(
        Wv + (size_t)l * 12288 * 192, WqkvT + (size_t)(l * 3 + 2) * WQKV, 12288, 192);
    transpose_f2b<<<dim3(6, 384), 256, 0, stream>>>(
        Wo + (size_t)l * 192 * 12288, WoT + (size_t)l * 12288 * 192, 192, 12288);
  }

  for (int l = 0; l < 2; ++l) {
    // z_in = relu(LAM * x @ D^T) -> zbuf shifted rows [b*1025+1 ..]
    // 256^2 tile: grid 16x48 -> 1-D 768, XCD-rect 16x x 6y (B 2.4 MB/XCD)
    gemm_bt2<unsigned short, true, 1, false, false, 16, 48, 1, 16, 6>
        <<<768, 512, 0, stream>>>(xb, Dbt, zbuf, nullptr, 768, 12288, LAM);
    // k/v row-0 prefill (= zero-context bias row); qb fully written by qkv s=0.
    fill_bias<<<3072, 256, 0, stream>>>(kb, bk + (size_t)l * 192, 192);
    fill_bias<<<3072, 256, 0, stream>>>(vb, bv + (size_t)l * 192, 192);
    // P2 zero-prefill (rows (b,0) of k/v planes must read as 0 in the merge)
    fill_bias<<<9216, 256, 0, stream>>>(P2, nullptr, 192);
    // atomic-free fused q/k/v: split 0 -> final bufs, split 1 -> P2; merge.
    gemm_qkv<<<384, 256, 0, stream>>>(
        zbuf, WqkvT + (size_t)(l * 3) * WQKV,
        bq + (size_t)l * 192, bk + (size_t)l * 192, bv + (size_t)l * 192,
        qb, kb, vb, P2);
    qkv_merge<<<2304, 256, 0, stream>>>(P2, qb, kb, vb);
    // Attention (z_in in zbuf is dead now; attnP scratch aliases it)
    attn_pass1<<<2304, 256, 0, stream>>>(qb, kb, vb, attnP);
    attn_merge<<<4096, 192, 0, stream>>>(attnP, ob);
    // z_pred_ = relu(o @ Wo + bo) -> zpred_ (aliases zbuf; attnP dead)
    gemm_bt2<unsigned short, true, 0, true, false, 16, 48, 1, 16, 6>
        <<<768, 512, 0, stream>>>(
        ob, WoT + (size_t)l * 12288 * 192, zpred_, bo + (size_t)l * 12288, 192, 12288, 1.0f);
    // Dz = z_pred_ @ D  (256^2, split-K=4 -> 192 blocks)
    fill_bias<<<12288, 256, 0, stream>>>(Dz, nullptr, 768);
    gemm_bt2<float, false, 0, false, true, 16, 3, 4, 8, 3>
        <<<192, 512, 0, stream>>>(zpred_, Dt, Dz, nullptr, 12288, 768, 1.0f);
    proj_update<<<4096, 256, 0, stream>>>(Dz, x, xb);
  }
  // z_novel = relu(LAM * x @ D^T) -> zbuf shifted rows
  gemm_bt2<unsigned short, true, 1, false, false, 16, 48, 1, 16, 6>
      <<<768, 512, 0, stream>>>(xb, Dbt, zbuf, nullptr, 768, 12288, LAM);
  topk_rows<<<4096, 256, 0, stream>>>(zbuf, idxo, valo);
  sparse_recons<<<4096, 256, 0, stream>>>(idxo, valo, x, xin, D, (float*)d_out);
}